// Round 2
// 764.072 us; speedup vs baseline: 1.0190x; 1.0190x over previous
//
#include <hip/hip_runtime.h>
#include <stdint.h>
#include <stddef.h>

// Problem constants: B=8, N=4096, D=1024
#define D_ 1024
#define NSEQ_ 4096
#define BATCH_ 8
#define BN_ (BATCH_ * NSEQ_)

typedef __attribute__((ext_vector_type(8))) short short8;
typedef __attribute__((ext_vector_type(4))) short short4_t;
typedef __attribute__((ext_vector_type(4))) float float4_t;

__device__ __forceinline__ short f2b(float f) {  // fp32 -> bf16 bits, RNE
  union { float f; uint32_t u; } x; x.f = f;
  uint32_t r = x.u + 0x7fffu + ((x.u >> 16) & 1u);
  return (short)(r >> 16);
}
__device__ __forceinline__ float b2f(short s) {
  union { float f; uint32_t u; } x; x.u = ((uint32_t)(uint16_t)s) << 16; return x.f;
}

// async global->LDS, 16B per lane; LDS dest is wave-uniform base + lane*16
__device__ __forceinline__ void gll16(const void* g, void* l) {
  auto gp = reinterpret_cast<const uint32_t __attribute__((address_space(1)))*>(
      reinterpret_cast<uintptr_t>(g));
  auto lp = reinterpret_cast<uint32_t __attribute__((address_space(3)))*>(
      reinterpret_cast<uintptr_t>(l));
  __builtin_amdgcn_global_load_lds(gp, lp, 16, 0, 0);
}

#define MFMA16(a, b, c) __builtin_amdgcn_mfma_f32_16x16x32_bf16(a, b, c, 0, 0, 0)

// ---------------------------------------------------------------------------
// Kernel A: x fp32 -> bf16 (memory-bound, 8 elems/thread)
// ---------------------------------------------------------------------------
__global__ void convert_x(const float* __restrict__ X, short* __restrict__ Xb) {
  const size_t i = (size_t)blockIdx.x * 256 + threadIdx.x;  // 8 elems each
  const float4_t* p = (const float4_t*)(X + i * 8);
  float4_t a = p[0], b = p[1];
  short8 o;
  o[0] = f2b(a.x); o[1] = f2b(a.y); o[2] = f2b(a.z); o[3] = f2b(a.w);
  o[4] = f2b(b.x); o[5] = f2b(b.y); o[6] = f2b(b.z); o[7] = f2b(b.w);
  *(short8*)(Xb + i * 8) = o;
}

// ---------------------------------------------------------------------------
// Kernel 0: weights (D,D) fp32 -> transposed bf16, INTERLEAVED layout:
//   Wint[(e>>4)*64 + z*16 + (e&15)][d] = W_z[d][e]
// so a 256-row B-tile of Wint holds 64 e-columns x all 4 weights, with each
// 16-row n-fragment single-weight (weight index = fragment index).
// ---------------------------------------------------------------------------
__global__ void transpose_convert_w(const float* __restrict__ w0, const float* __restrict__ w1,
                                    const float* __restrict__ w2, const float* __restrict__ w3,
                                    short* __restrict__ wT) {
  __shared__ float tile[32][33];
  const int z = blockIdx.z;
  const float* src = (z == 0) ? w0 : (z == 1) ? w1 : (z == 2) ? w2 : w3;
  const int d0 = blockIdx.y * 32, e0 = blockIdx.x * 32;
  const int tx = threadIdx.x, ty = threadIdx.y;
#pragma unroll
  for (int i = 0; i < 4; ++i) {
    int d = ty + i * 8;
    tile[d][tx] = src[(size_t)(d0 + d) * D_ + (e0 + tx)];
  }
  __syncthreads();
#pragma unroll
  for (int i = 0; i < 4; ++i) {
    int e = ty + i * 8;
    const int eg = e0 + e;
    const int row = ((eg >> 4) << 6) + (z << 4) + (eg & 15);
    wT[(size_t)row * D_ + (d0 + tx)] = f2b(tile[tx][e]);
  }
}

// ---------------------------------------------------------------------------
// Kernel 1: QUAD-weight GEMM as one 256x256-tile phased GEMM.
//   A = Xb (32768 x 1024), B = Wint (4096 x 1024, weight-interleaved).
// 512 threads = 8 waves (2 M x 4 N); per-wave output 128 rows x 64 B-rows
// (= 16 e-cols x 4 weights). BK=32, 4-slot LDS ring (128 KB), per step:
//   phase A: ds_read a0..3+b0..3 | stage A(t+2) | bar | lgkm0 | 16 MFMA | bar
//   phase B: ds_read a4..7       | stage B(t+2) | bar | lgkm0 | 16 MFMA |
//            s_waitcnt vmcnt(4)  (counted, never 0 in main loop) | bar
// Ring safety: stage of step t+2 targets slot (t+2)&3 whose last reads
// completed before the end-of-step-(t-1) barrier. vmcnt(4) at end of step t
// allows exactly this step's 4 loads (slot t+2) to stay in flight while
// guaranteeing slot t+1 is fully landed (per-wave FIFO count + barrier join).
// LDS T2 swizzle: k-slot ^= (row>>1)&3 applied BOTH on the global source of
// global_load_lds (LDS stays linear, rule 21) and on the ds_read address:
// 8-way read conflict -> 2-way (free).
// ---------------------------------------------------------------------------
__global__ __launch_bounds__(512, 2) void gemm_x4w(
    const short* __restrict__ Xb, const short* __restrict__ Wint,
    short* __restrict__ qout, short* __restrict__ kT, short* __restrict__ vT,
    float* __restrict__ ssk, float* __restrict__ ssv) {
  // 4 ring slots x (A 8192 shorts + B 8192 shorts) = 128 KB.
  // Epilogue 2 reuses the front as a 64 x 264 transpose buffer.
  __shared__ short ring[4 * 16384];

  const int t = threadIdx.x;
  const int w = t >> 6;        // wave 0..7
  const int lane = t & 63;
  const int l16 = lane & 15;
  const int quad = lane >> 4;  // k-chunk selector (k = quad*8 within BK=32)
  const int wm = w >> 2;       // 0..1 : 128-row half of A-tile
  const int wn = w & 3;        // 0..3 : 64-row quarter of B-tile

  // XCD-aware bijective swizzle (2048 blocks % 8 == 0)
  const int bid = blockIdx.x;
  const int lin = (bid & 7) * 256 + (bid >> 3);
  const int mt = lin >> 4;            // 0..127 row tiles (256 rows each)
  const int nt = lin & 15;            // 0..15 interleaved-W tiles
  const int M0 = mt * 256;
  const int N0 = nt * 256;            // over Wint's 4096 rows
  const int E0 = nt * 64;             // e-range of this block

  const float4_t fz = {0.f, 0.f, 0.f, 0.f};
  float4_t acc[8][4];  // [m-frag][weight] = 128 VGPRs
#pragma unroll
  for (int i = 0; i < 8; ++i)
#pragma unroll
    for (int j = 0; j < 4; ++j) acc[i][j] = fz;

  // ---- precomputed, loop-invariant addresses ----
  // staging: wave w owns units uu = 2w, 2w+1 (16 rows x 64 B each)
  size_t goffA[2], goffB[2];
  int ldsu[2];
#pragma unroll
  for (int r = 0; r < 2; ++r) {
    const int uu = w * 2 + r;
    const int row = uu * 16 + (lane >> 2);
    const int sp = (lane & 3) ^ ((row >> 1) & 3);   // pre-swizzled k-slot
    goffA[r] = (size_t)(M0 + row) * 1024 + sp * 8;
    goffB[r] = (size_t)(N0 + row) * 1024 + sp * 8;
    ldsu[r] = uu * 512;  // shorts
  }
  // ds_read offsets (shorts), swizzled to match
  int aoff[8], boff[4];
#pragma unroll
  for (int i = 0; i < 8; ++i) {
    const int row = wm * 128 + i * 16 + l16;
    aoff[i] = row * 32 + ((quad ^ ((row >> 1) & 3)) << 3);
  }
#pragma unroll
  for (int j = 0; j < 4; ++j) {
    const int row = wn * 64 + j * 16 + l16;
    boff[j] = row * 32 + ((quad ^ ((row >> 1) & 3)) << 3);
  }

  // ---- prologue: stage steps 0 and 1 (slots 0,1); 8 loads/lane in flight ----
#pragma unroll
  for (int r = 0; r < 2; ++r) gll16(Xb + goffA[r], ring + ldsu[r]);
#pragma unroll
  for (int r = 0; r < 2; ++r) gll16(Wint + goffB[r], ring + 8192 + ldsu[r]);
#pragma unroll
  for (int r = 0; r < 2; ++r) gll16(Xb + goffA[r] + 32, ring + 16384 + ldsu[r]);
#pragma unroll
  for (int r = 0; r < 2; ++r) gll16(Wint + goffB[r] + 32, ring + 16384 + 8192 + ldsu[r]);
  asm volatile("s_waitcnt vmcnt(4)" ::: "memory");  // step 0 landed; step 1 may fly
  __builtin_amdgcn_s_barrier();

  // ---- main loop: 32 K-steps of 32 ----
#pragma unroll 1
  for (int tt = 0; tt < 32; ++tt) {
    const short* As = ring + (tt & 3) * 16384;
    const short* Bs = As + 8192;
    short8 aF[8], bF[4];

    // ===== phase A: read a0..3 + b0..3, stage A(tt+2) =====
#pragma unroll
    for (int i = 0; i < 4; ++i) aF[i] = *(const short8*)&As[aoff[i]];
#pragma unroll
    for (int j = 0; j < 4; ++j) bF[j] = *(const short8*)&Bs[boff[j]];
    if (tt < 30) {
      short* dA = ring + ((tt + 2) & 3) * 16384;
      const int k0 = (tt + 2) * 32;
#pragma unroll
      for (int r = 0; r < 2; ++r) gll16(Xb + goffA[r] + k0, dA + ldsu[r]);
    }
    __builtin_amdgcn_s_barrier();
    asm volatile("s_waitcnt lgkmcnt(0)" ::: "memory");
    __builtin_amdgcn_s_setprio(1);
#pragma unroll
    for (int i = 0; i < 4; ++i)
#pragma unroll
      for (int j = 0; j < 4; ++j) acc[i][j] = MFMA16(aF[i], bF[j], acc[i][j]);
    __builtin_amdgcn_s_setprio(0);
    __builtin_amdgcn_s_barrier();

    // ===== phase B: read a4..7, stage B(tt+2), counted vmcnt =====
#pragma unroll
    for (int i = 4; i < 8; ++i) aF[i] = *(const short8*)&As[aoff[i]];
    if (tt < 30) {
      short* dB = ring + ((tt + 2) & 3) * 16384 + 8192;
      const int k0 = (tt + 2) * 32;
#pragma unroll
      for (int r = 0; r < 2; ++r) gll16(Wint + goffB[r] + k0, dB + ldsu[r]);
    }
    __builtin_amdgcn_s_barrier();
    asm volatile("s_waitcnt lgkmcnt(0)" ::: "memory");
    __builtin_amdgcn_s_setprio(1);
#pragma unroll
    for (int i = 4; i < 8; ++i)
#pragma unroll
      for (int j = 0; j < 4; ++j) acc[i][j] = MFMA16(aF[i], bF[j], acc[i][j]);
    __builtin_amdgcn_s_setprio(0);
    if (tt < 30) {
      asm volatile("s_waitcnt vmcnt(4)" ::: "memory");  // this step's 4 loads may fly
    } else if (tt == 30) {
      asm volatile("s_waitcnt vmcnt(0)" ::: "memory");  // final drain (last stage was tt=29)
    }
    __builtin_amdgcn_s_barrier();
  }

  // --- epilogue 1: query = relu(qr)*relu(qi) -> bf16, [bn][e] (no LDS) ---
  const int e = E0 + wn * 16 + l16;
#pragma unroll
  for (int i = 0; i < 8; ++i) {
    const int rowg = M0 + wm * 128 + i * 16 + quad * 4;
#pragma unroll
    for (int rr = 0; rr < 4; ++rr) {
      float v = fmaxf(acc[i][0][rr], 0.f) * fmaxf(acc[i][1][rr], 0.f);
      qout[(size_t)(rowg + rr) * 1024 + e] = f2b(v);
    }
  }

  // --- epilogue 2: k,v transposed -> [b][e][n] + sumsq ---
  short* T = ring;          // 64 x 264 transpose buffer (16896 shorts)
  const int b = M0 >> 12;   // 256-row tile lies within one batch
  const int n0 = M0 & 4095;
#pragma unroll
  for (int wt = 2; wt < 4; ++wt) {
    short* dst = (wt == 2) ? kT : vT;
    float* ss = (wt == 2) ? ssk : ssv;
    __syncthreads();  // full sync (protects LDS reuse between rounds)
    // registers -> LDS transposed: T[e_local][n_local], packed 4 rr -> b64
#pragma unroll
    for (int i = 0; i < 8; ++i) {
      const int nl = wm * 128 + i * 16 + quad * 4;
      const int el = wn * 16 + l16;
      short4_t pk;
#pragma unroll
      for (int rr = 0; rr < 4; ++rr) pk[rr] = f2b(acc[i][wt][rr]);
      *(short4_t*)&T[el * 264 + nl] = pk;
    }
    __syncthreads();
    // drain rows of T -> global [b][e][n] (coalesced 512B/row) + sumsq
#pragma unroll
    for (int it = 0; it < 4; ++it) {
      const int ee = it * 16 + (t >> 5);
      const int nch = (t & 31) * 8;
      short8 vv = *(const short8*)&T[ee * 264 + nch];
      *(short8*)&dst[((size_t)b * 1024 + E0 + ee) * 4096 + n0 + nch] = vv;
      float s = 0.f;
#pragma unroll
      for (int x2 = 0; x2 < 8; ++x2) { float f = b2f(vv[x2]); s += f * f; }
      s += __shfl_xor(s, 1, 32);
      s += __shfl_xor(s, 2, 32);
      s += __shfl_xor(s, 4, 32);
      s += __shfl_xor(s, 8, 32);
      s += __shfl_xor(s, 16, 32);
      if ((t & 31) == 0) atomicAdd(&ss[b * 1024 + E0 + ee], s);
    }
  }
}

// ---------------------------------------------------------------------------
// Kernel 2: inv norms: inv[i] = 1/(sqrt(ss[i]) + 1e-5), 2*B*D entries
// ---------------------------------------------------------------------------
__global__ void finish_norms(const float* __restrict__ ss, float* __restrict__ inv) {
  const int i = blockIdx.x * 256 + threadIdx.x;
  if (i < 2 * BATCH_ * D_) inv[i] = 1.f / (sqrtf(ss[i]) + 1e-5f);
}

// ---------------------------------------------------------------------------
// Kernel 3: generic batched gemm_bt: C[m][n] = sum_k A[m][k]*B[n][k], bf16 in,
// both operands row-major with k contiguous (ld == K). 128x128 tile, BK=32.
// mode 0: out bf16 = relu(C * rs[m] * cs[n])   (kv^T epilogue)
// mode 1: out fp32 = C                          (final output)
// ---------------------------------------------------------------------------
__global__ __launch_bounds__(256, 2) void gemm_bt(
    const short* __restrict__ A, const short* __restrict__ Bm,
    size_t sAb, size_t sBb, int K, int mode,
    const float* __restrict__ rsb, const float* __restrict__ csb,
    void* __restrict__ outp) {
  __shared__ short As[128 * 32];
  __shared__ short Bs[128 * 32];
  const int t = threadIdx.x;
  const int w = t >> 6;
  const int lane = t & 63;
  const int l16 = lane & 15;
  const int quad = lane >> 4;
  const int wm = w >> 1, wn = w & 1;
  const int M0 = blockIdx.y * 128, N0 = blockIdx.x * 128, b = blockIdx.z;
  const short* Ab = A + (size_t)b * sAb;
  const short* Bb = Bm + (size_t)b * sBb;

  const float4_t fz = {0.f, 0.f, 0.f, 0.f};
  float4_t acc[4][4];
#pragma unroll
  for (int i = 0; i < 4; ++i)
#pragma unroll
    for (int j = 0; j < 4; ++j) acc[i][j] = fz;

  const int rowq = lane >> 2;
  const int chunk = (lane & 3) * 8;

  for (int k0 = 0; k0 < K; k0 += 32) {
#pragma unroll
    for (int r = 0; r < 4; ++r) {
      const int q = w * 4 + r;  // 0..15, wave-uniform
      if (q < 8) {
        const int row = q * 16 + rowq;
        gll16(Ab + (size_t)(M0 + row) * K + (k0 + chunk), &As[q * 512]);
      } else {
        const int row = (q - 8) * 16 + rowq;
        gll16(Bb + (size_t)(N0 + row) * K + (k0 + chunk), &Bs[(q - 8) * 512]);
      }
    }
    __syncthreads();
    short8 aF[4], bF[4];
#pragma unroll
    for (int i = 0; i < 4; ++i)
      aF[i] = *(const short8*)&As[(wm * 64 + i * 16 + l16) * 32 + quad * 8];
#pragma unroll
    for (int j = 0; j < 4; ++j)
      bF[j] = *(const short8*)&Bs[(wn * 64 + j * 16 + l16) * 32 + quad * 8];
#pragma unroll
    for (int i = 0; i < 4; ++i)
#pragma unroll
      for (int j = 0; j < 4; ++j) acc[i][j] = MFMA16(aF[i], bF[j], acc[i][j]);
    __syncthreads();
  }

  if (mode == 0) {
    short* ob = (short*)outp + (size_t)b * D_ * D_;
    const float* rs = rsb + b * D_ + M0;
    const float* cs = csb + b * D_ + N0;
#pragma unroll
    for (int i = 0; i < 4; ++i) {
      const int rl = wm * 64 + i * 16 + quad * 4;
#pragma unroll
      for (int j = 0; j < 4; ++j) {
        const int cl = wn * 64 + j * 16 + l16;
        const float csc = cs[cl];
#pragma unroll
        for (int rr = 0; rr < 4; ++rr) {
          float v = acc[i][j][rr] * rs[rl + rr] * csc;
          v = fmaxf(v, 0.f);
          ob[(size_t)(M0 + rl + rr) * 1024 + (N0 + cl)] = f2b(v);
        }
      }
    }
  } else {
    float* of = (float*)outp + (size_t)b * NSEQ_ * D_;
#pragma unroll
    for (int i = 0; i < 4; ++i) {
      const int rl = wm * 64 + i * 16 + quad * 4;
#pragma unroll
      for (int j = 0; j < 4; ++j) {
        const int cl = wn * 64 + j * 16 + l16;
#pragma unroll
        for (int rr = 0; rr < 4; ++rr)
          of[(size_t)(M0 + rl + rr) * 1024 + (N0 + cl)] = acc[i][j][rr];
      }
    }
  }
}

// ---------------------------------------------------------------------------
extern "C" void kernel_launch(void* const* d_in, const int* in_sizes, int n_in,
                              void* d_out, int out_size, void* d_ws, size_t ws_size,
                              hipStream_t stream) {
  const float* x = (const float*)d_in[0];
  const float* wqr = (const float*)d_in[1];
  const float* wqi = (const float*)d_in[2];
  const float* wk = (const float*)d_in[3];
  const float* wv = (const float*)d_in[4];

  // workspace layout (all bf16 stored as short)
  short* wT = (short*)d_ws;                          // 4 * D*D            (8 MB)
  short* qb = wT + (size_t)4 * D_ * D_;              // BN * D             (64 MB)
  short* kT = qb + (size_t)BN_ * D_;                 // B * D * N          (64 MB)
  short* vT = kT + (size_t)BATCH_ * D_ * NSEQ_;      // B * D * N          (64 MB)
  short* kvT = vT + (size_t)BATCH_ * D_ * NSEQ_;     // B * D * D          (16 MB)
  float* ssk = (float*)(kvT + (size_t)BATCH_ * D_ * D_);  // B*D
  float* ssv = ssk + BATCH_ * D_;                    // B*D  (contiguous with ssk)
  float* invk = ssv + BATCH_ * D_;                   // B*D
  float* invv = invk + BATCH_ * D_;                  // B*D  (contiguous with invk)

  // bf16 x parked in d_out (128 MB fp32 buffer; only written by the final
  // GEMM, which runs strictly after x's last use)
  short* xb = (short*)d_out;

  hipMemsetAsync(ssk, 0, (size_t)2 * BATCH_ * D_ * sizeof(float), stream);

  // x fp32 -> bf16 : 33.5M elems / 8 per thread / 256 per block
  convert_x<<<dim3(16384), 256, 0, stream>>>(x, xb);

  transpose_convert_w<<<dim3(32, 32, 4), dim3(32, 8), 0, stream>>>(wqr, wqi, wk, wv, wT);

  // all four x@W GEMMs as one 256x256-tile phased GEMM over interleaved W
  gemm_x4w<<<dim3(2048), 512, 0, stream>>>(xb, wT, qb, kT, vT, ssk, ssv);

  finish_norms<<<dim3(64), 256, 0, stream>>>(ssk, invk);

  // kv^T[b][e][d] = relu( (sum_n V[n,e]K[n,d]) * invv[e] * invk[d] )
  gemm_bt<<<dim3(8, 8, 8), 256, 0, stream>>>(
      vT, kT, (size_t)D_ * NSEQ_, (size_t)D_ * NSEQ_, 4096, 0, invv, invk, (void*)kvT);

  // out[b][n][e] = sum_d query[n,d] * kv^T[e,d]   (fp32)
  gemm_bt<<<dim3(8, 32, 8), 256, 0, stream>>>(
      qb, kvT, (size_t)NSEQ_ * D_, (size_t)D_ * D_, 1024, 1, nullptr, nullptr, d_out);
}

// Round 3
// 727.605 us; speedup vs baseline: 1.0700x; 1.0501x over previous
//
#include <hip/hip_runtime.h>
#include <stdint.h>
#include <stddef.h>

// Problem constants: B=8, N=4096, D=1024
#define D_ 1024
#define NSEQ_ 4096
#define BATCH_ 8
#define BN_ (BATCH_ * NSEQ_)

typedef __attribute__((ext_vector_type(8))) short short8;
typedef __attribute__((ext_vector_type(4))) short short4_t;
typedef __attribute__((ext_vector_type(4))) float float4_t;

__device__ __forceinline__ short f2b(float f) {  // fp32 -> bf16 bits, RNE
  union { float f; uint32_t u; } x; x.f = f;
  uint32_t r = x.u + 0x7fffu + ((x.u >> 16) & 1u);
  return (short)(r >> 16);
}
__device__ __forceinline__ float b2f(short s) {
  union { float f; uint32_t u; } x; x.u = ((uint32_t)(uint16_t)s) << 16; return x.f;
}

// async global->LDS, 16B per lane; LDS dest is wave-uniform base + lane*16
__device__ __forceinline__ void gll16(const void* g, void* l) {
  auto gp = reinterpret_cast<const uint32_t __attribute__((address_space(1)))*>(
      reinterpret_cast<uintptr_t>(g));
  auto lp = reinterpret_cast<uint32_t __attribute__((address_space(3)))*>(
      reinterpret_cast<uintptr_t>(l));
  __builtin_amdgcn_global_load_lds(gp, lp, 16, 0, 0);
}

#define MFMA16(a, b, c) __builtin_amdgcn_mfma_f32_16x16x32_bf16(a, b, c, 0, 0, 0)

// ---------------------------------------------------------------------------
// Kernel A: x fp32 -> bf16 (memory-bound, 8 elems/thread).
// X is read exactly once in the whole pipeline -> non-temporal loads keep it
// from evicting useful lines from L2/L3.
// ---------------------------------------------------------------------------
__global__ void convert_x(const float* __restrict__ X, short* __restrict__ Xb) {
  const size_t i = (size_t)blockIdx.x * 256 + threadIdx.x;  // 8 elems each
  const float4_t* p = (const float4_t*)(X + i * 8);
  float4_t a = __builtin_nontemporal_load(p);
  float4_t b = __builtin_nontemporal_load(p + 1);
  short8 o;
  o[0] = f2b(a.x); o[1] = f2b(a.y); o[2] = f2b(a.z); o[3] = f2b(a.w);
  o[4] = f2b(b.x); o[5] = f2b(b.y); o[6] = f2b(b.z); o[7] = f2b(b.w);
  *(short8*)(Xb + i * 8) = o;
}

// ---------------------------------------------------------------------------
// Kernel 0: weights (D,D) fp32 -> transposed bf16, INTERLEAVED layout:
//   Wint[(e>>4)*64 + z*16 + (e&15)][d] = W_z[d][e]
// so a 256-row B-tile of Wint holds 64 e-columns x all 4 weights, with each
// 16-row n-fragment single-weight (weight index = fragment index).
// fp32 weights are read exactly once -> non-temporal loads.
// ---------------------------------------------------------------------------
__global__ void transpose_convert_w(const float* __restrict__ w0, const float* __restrict__ w1,
                                    const float* __restrict__ w2, const float* __restrict__ w3,
                                    short* __restrict__ wT) {
  __shared__ float tile[32][33];
  const int z = blockIdx.z;
  const float* src = (z == 0) ? w0 : (z == 1) ? w1 : (z == 2) ? w2 : w3;
  const int d0 = blockIdx.y * 32, e0 = blockIdx.x * 32;
  const int tx = threadIdx.x, ty = threadIdx.y;
#pragma unroll
  for (int i = 0; i < 4; ++i) {
    int d = ty + i * 8;
    tile[d][tx] = __builtin_nontemporal_load(&src[(size_t)(d0 + d) * D_ + (e0 + tx)]);
  }
  __syncthreads();
#pragma unroll
  for (int i = 0; i < 4; ++i) {
    int e = ty + i * 8;
    const int eg = e0 + e;
    const int row = ((eg >> 4) << 6) + (z << 4) + (eg & 15);
    wT[(size_t)row * D_ + (d0 + tx)] = f2b(tile[tx][e]);
  }
}

// ---------------------------------------------------------------------------
// Kernel 1: QUAD-weight GEMM as one 256x256-tile phased GEMM.
//   A = Xb (32768 x 1024), B = Wint (4096 x 1024, weight-interleaved).
// 512 threads = 8 waves (2 M x 4 N); per-wave output 128 rows x 64 B-rows
// (= 16 e-cols x 4 weights). BK=32, 4-slot LDS ring (128 KB), per step:
//   phase A: ds_read a0..3+b0..3 | stage A(t+2) | bar | lgkm0 | 16 MFMA | bar
//   phase B: ds_read a4..7       | stage B(t+2) | bar | lgkm0 | 16 MFMA |
//            s_waitcnt vmcnt(4)  (counted, never 0 in main loop) | bar
// Ring safety: stage of step t+2 targets slot (t+2)&3 whose last reads
// completed before the end-of-step-(t-1) barrier. vmcnt(4) at end of step t
// allows exactly this step's 4 loads (slot t+2) to stay in flight while
// guaranteeing slot t+1 is fully landed (per-wave FIFO count + barrier join).
// LDS T2 swizzle: k-slot ^= (row>>1)&3 on BOTH the global source of
// global_load_lds (LDS stays linear, rule 21) and the ds_read address.
//
// R3 change: L2-chunked block mapping. Previous mapping made nt fastest
// within an XCD -> 32 concurrent CUs touched all 16 B-tiles (8MB) -> L2
// thrash, every block re-pulled A+B tiles from L3/HBM (fabric-BW-bound at
// ~6.6 TB/s aggregate, 39 us/block). New mapping: per-XCD chunks of
// 8 mtl x 4 ntl -> concurrent working set ~4MB A + 2MB B, A reused x4 and
// B x8 from L2.
// ---------------------------------------------------------------------------
__global__ __launch_bounds__(512, 2) void gemm_x4w(
    const short* __restrict__ Xb, const short* __restrict__ Wint,
    short* __restrict__ qout, short* __restrict__ kT, short* __restrict__ vT,
    float* __restrict__ ssk, float* __restrict__ ssv) {
  // 4 ring slots x (A 8192 shorts + B 8192 shorts) = 128 KB.
  // Epilogue 2 reuses the front as a 64 x 264 transpose buffer.
  __shared__ short ring[4 * 16384];

  const int t = threadIdx.x;
  const int w = t >> 6;        // wave 0..7
  const int lane = t & 63;
  const int l16 = lane & 15;
  const int quad = lane >> 4;  // k-chunk selector (k = quad*8 within BK=32)
  const int wm = w >> 2;       // 0..1 : 128-row half of A-tile
  const int wn = w & 3;        // 0..3 : 64-row quarter of B-tile

  // L2-chunked XCD-aware mapping (2048 blocks, HW round-robins bid%8 -> XCD):
  //   per XCD: j in [0,256); chunks of 32 = 8 mtl x 4 ntl.
  const int bid = blockIdx.x;
  const int c = bid & 7;                 // XCD
  const int j = bid >> 3;                // 0..255 within XCD
  const int ch = j >> 5;                 // 8 chunks of 32 blocks
  const int mtl = (ch & 1) * 8 + (j & 7);          // 0..15
  const int ntl = (ch >> 1) * 4 + ((j >> 3) & 3);  // 0..15
  const int mt = c * 16 + mtl;           // 0..127 row tiles (256 rows each)
  const int nt = ntl;                    // 0..15 interleaved-W tiles
  const int M0 = mt * 256;
  const int N0 = nt * 256;               // over Wint's 4096 rows
  const int E0 = nt * 64;                // e-range of this block

  const float4_t fz = {0.f, 0.f, 0.f, 0.f};
  float4_t acc[8][4];  // [m-frag][weight] = 128 VGPRs
#pragma unroll
  for (int i = 0; i < 8; ++i)
#pragma unroll
    for (int j2 = 0; j2 < 4; ++j2) acc[i][j2] = fz;

  // ---- precomputed, loop-invariant addresses ----
  // staging: wave w owns units uu = 2w, 2w+1 (16 rows x 64 B each)
  size_t goffA[2], goffB[2];
  int ldsu[2];
#pragma unroll
  for (int r = 0; r < 2; ++r) {
    const int uu = w * 2 + r;
    const int row = uu * 16 + (lane >> 2);
    const int sp = (lane & 3) ^ ((row >> 1) & 3);   // pre-swizzled k-slot
    goffA[r] = (size_t)(M0 + row) * 1024 + sp * 8;
    goffB[r] = (size_t)(N0 + row) * 1024 + sp * 8;
    ldsu[r] = uu * 512;  // shorts
  }
  // ds_read offsets (shorts), swizzled to match
  int aoff[8], boff[4];
#pragma unroll
  for (int i = 0; i < 8; ++i) {
    const int row = wm * 128 + i * 16 + l16;
    aoff[i] = row * 32 + ((quad ^ ((row >> 1) & 3)) << 3);
  }
#pragma unroll
  for (int j2 = 0; j2 < 4; ++j2) {
    const int row = wn * 64 + j2 * 16 + l16;
    boff[j2] = row * 32 + ((quad ^ ((row >> 1) & 3)) << 3);
  }

  // ---- prologue: stage steps 0 and 1 (slots 0,1); 8 loads/lane in flight ----
#pragma unroll
  for (int r = 0; r < 2; ++r) gll16(Xb + goffA[r], ring + ldsu[r]);
#pragma unroll
  for (int r = 0; r < 2; ++r) gll16(Wint + goffB[r], ring + 8192 + ldsu[r]);
#pragma unroll
  for (int r = 0; r < 2; ++r) gll16(Xb + goffA[r] + 32, ring + 16384 + ldsu[r]);
#pragma unroll
  for (int r = 0; r < 2; ++r) gll16(Wint + goffB[r] + 32, ring + 16384 + 8192 + ldsu[r]);
  asm volatile("s_waitcnt vmcnt(4)" ::: "memory");  // step 0 landed; step 1 may fly
  __builtin_amdgcn_s_barrier();

  // ---- main loop: 32 K-steps of 32 ----
#pragma unroll 1
  for (int tt = 0; tt < 32; ++tt) {
    const short* As = ring + (tt & 3) * 16384;
    const short* Bs = As + 8192;
    short8 aF[8], bF[4];

    // ===== phase A: read a0..3 + b0..3, stage A(tt+2) =====
#pragma unroll
    for (int i = 0; i < 4; ++i) aF[i] = *(const short8*)&As[aoff[i]];
#pragma unroll
    for (int j2 = 0; j2 < 4; ++j2) bF[j2] = *(const short8*)&Bs[boff[j2]];
    if (tt < 30) {
      short* dA = ring + ((tt + 2) & 3) * 16384;
      const int k0 = (tt + 2) * 32;
#pragma unroll
      for (int r = 0; r < 2; ++r) gll16(Xb + goffA[r] + k0, dA + ldsu[r]);
    }
    __builtin_amdgcn_s_barrier();
    asm volatile("s_waitcnt lgkmcnt(0)" ::: "memory");
    __builtin_amdgcn_s_setprio(1);
#pragma unroll
    for (int i = 0; i < 4; ++i)
#pragma unroll
      for (int j2 = 0; j2 < 4; ++j2) acc[i][j2] = MFMA16(aF[i], bF[j2], acc[i][j2]);
    __builtin_amdgcn_s_setprio(0);
    __builtin_amdgcn_s_barrier();

    // ===== phase B: read a4..7, stage B(tt+2), counted vmcnt =====
#pragma unroll
    for (int i = 4; i < 8; ++i) aF[i] = *(const short8*)&As[aoff[i]];
    if (tt < 30) {
      short* dB = ring + ((tt + 2) & 3) * 16384 + 8192;
      const int k0 = (tt + 2) * 32;
#pragma unroll
      for (int r = 0; r < 2; ++r) gll16(Wint + goffB[r] + k0, dB + ldsu[r]);
    }
    __builtin_amdgcn_s_barrier();
    asm volatile("s_waitcnt lgkmcnt(0)" ::: "memory");
    __builtin_amdgcn_s_setprio(1);
#pragma unroll
    for (int i = 4; i < 8; ++i)
#pragma unroll
      for (int j2 = 0; j2 < 4; ++j2) acc[i][j2] = MFMA16(aF[i], bF[j2], acc[i][j2]);
    __builtin_amdgcn_s_setprio(0);
    if (tt < 30) {
      asm volatile("s_waitcnt vmcnt(4)" ::: "memory");  // this step's 4 loads may fly
    } else if (tt == 30) {
      asm volatile("s_waitcnt vmcnt(0)" ::: "memory");  // final drain (last stage was tt=29)
    }
    __builtin_amdgcn_s_barrier();
  }

  // --- epilogue 1: query = relu(qr)*relu(qi) -> bf16, [bn][e] (no LDS) ---
  const int e = E0 + wn * 16 + l16;
#pragma unroll
  for (int i = 0; i < 8; ++i) {
    const int rowg = M0 + wm * 128 + i * 16 + quad * 4;
#pragma unroll
    for (int rr = 0; rr < 4; ++rr) {
      float v = fmaxf(acc[i][0][rr], 0.f) * fmaxf(acc[i][1][rr], 0.f);
      qout[(size_t)(rowg + rr) * 1024 + e] = f2b(v);
    }
  }

  // --- epilogue 2: k,v transposed -> [b][e][n] + sumsq ---
  short* T = ring;          // 64 x 264 transpose buffer (16896 shorts)
  const int b = M0 >> 12;   // 256-row tile lies within one batch
  const int n0 = M0 & 4095;
#pragma unroll
  for (int wt = 2; wt < 4; ++wt) {
    short* dst = (wt == 2) ? kT : vT;
    float* ss = (wt == 2) ? ssk : ssv;
    __syncthreads();  // full sync (protects LDS reuse between rounds)
    // registers -> LDS transposed: T[e_local][n_local], packed 4 rr -> b64
#pragma unroll
    for (int i = 0; i < 8; ++i) {
      const int nl = wm * 128 + i * 16 + quad * 4;
      const int el = wn * 16 + l16;
      short4_t pk;
#pragma unroll
      for (int rr = 0; rr < 4; ++rr) pk[rr] = f2b(acc[i][wt][rr]);
      *(short4_t*)&T[el * 264 + nl] = pk;
    }
    __syncthreads();
    // drain rows of T -> global [b][e][n] (coalesced 512B/row) + sumsq
#pragma unroll
    for (int it = 0; it < 4; ++it) {
      const int ee = it * 16 + (t >> 5);
      const int nch = (t & 31) * 8;
      short8 vv = *(const short8*)&T[ee * 264 + nch];
      *(short8*)&dst[((size_t)b * 1024 + E0 + ee) * 4096 + n0 + nch] = vv;
      float s = 0.f;
#pragma unroll
      for (int x2 = 0; x2 < 8; ++x2) { float f = b2f(vv[x2]); s += f * f; }
      s += __shfl_xor(s, 1, 32);
      s += __shfl_xor(s, 2, 32);
      s += __shfl_xor(s, 4, 32);
      s += __shfl_xor(s, 8, 32);
      s += __shfl_xor(s, 16, 32);
      if ((t & 31) == 0) atomicAdd(&ss[b * 1024 + E0 + ee], s);
    }
  }
}

// ---------------------------------------------------------------------------
// Kernel 2: inv norms: inv[i] = 1/(sqrt(ss[i]) + 1e-5), 2*B*D entries
// ---------------------------------------------------------------------------
__global__ void finish_norms(const float* __restrict__ ss, float* __restrict__ inv) {
  const int i = blockIdx.x * 256 + threadIdx.x;
  if (i < 2 * BATCH_ * D_) inv[i] = 1.f / (sqrtf(ss[i]) + 1e-5f);
}

// ---------------------------------------------------------------------------
// Kernel 3: generic batched gemm_bt: C[m][n] = sum_k A[m][k]*B[n][k], bf16 in,
// both operands row-major with k contiguous (ld == K). 128x128 tile, BK=32.
// mode 0: out bf16 = relu(C * rs[m] * cs[n])   (kv^T epilogue)
// mode 1: out fp32 = C (final output; never re-read -> non-temporal stores)
// ---------------------------------------------------------------------------
__global__ __launch_bounds__(256, 2) void gemm_bt(
    const short* __restrict__ A, const short* __restrict__ Bm,
    size_t sAb, size_t sBb, int K, int mode,
    const float* __restrict__ rsb, const float* __restrict__ csb,
    void* __restrict__ outp) {
  __shared__ short As[128 * 32];
  __shared__ short Bs[128 * 32];
  const int t = threadIdx.x;
  const int w = t >> 6;
  const int lane = t & 63;
  const int l16 = lane & 15;
  const int quad = lane >> 4;
  const int wm = w >> 1, wn = w & 1;
  const int M0 = blockIdx.y * 128, N0 = blockIdx.x * 128, b = blockIdx.z;
  const short* Ab = A + (size_t)b * sAb;
  const short* Bb = Bm + (size_t)b * sBb;

  const float4_t fz = {0.f, 0.f, 0.f, 0.f};
  float4_t acc[4][4];
#pragma unroll
  for (int i = 0; i < 4; ++i)
#pragma unroll
    for (int j = 0; j < 4; ++j) acc[i][j] = fz;

  const int rowq = lane >> 2;
  const int chunk = (lane & 3) * 8;

  for (int k0 = 0; k0 < K; k0 += 32) {
#pragma unroll
    for (int r = 0; r < 4; ++r) {
      const int q = w * 4 + r;  // 0..15, wave-uniform
      if (q < 8) {
        const int row = q * 16 + rowq;
        gll16(Ab + (size_t)(M0 + row) * K + (k0 + chunk), &As[q * 512]);
      } else {
        const int row = (q - 8) * 16 + rowq;
        gll16(Bb + (size_t)(N0 + row) * K + (k0 + chunk), &Bs[(q - 8) * 512]);
      }
    }
    __syncthreads();
    short8 aF[4], bF[4];
#pragma unroll
    for (int i = 0; i < 4; ++i)
      aF[i] = *(const short8*)&As[(wm * 64 + i * 16 + l16) * 32 + quad * 8];
#pragma unroll
    for (int j = 0; j < 4; ++j)
      bF[j] = *(const short8*)&Bs[(wn * 64 + j * 16 + l16) * 32 + quad * 8];
#pragma unroll
    for (int i = 0; i < 4; ++i)
#pragma unroll
      for (int j = 0; j < 4; ++j) acc[i][j] = MFMA16(aF[i], bF[j], acc[i][j]);
    __syncthreads();
  }

  if (mode == 0) {
    short* ob = (short*)outp + (size_t)b * D_ * D_;
    const float* rs = rsb + b * D_ + M0;
    const float* cs = csb + b * D_ + N0;
#pragma unroll
    for (int i = 0; i < 4; ++i) {
      const int rl = wm * 64 + i * 16 + quad * 4;
#pragma unroll
      for (int j = 0; j < 4; ++j) {
        const int cl = wn * 64 + j * 16 + l16;
        const float csc = cs[cl];
#pragma unroll
        for (int rr = 0; rr < 4; ++rr) {
          float v = acc[i][j][rr] * rs[rl + rr] * csc;
          v = fmaxf(v, 0.f);
          ob[(size_t)(M0 + rl + rr) * 1024 + (N0 + cl)] = f2b(v);
        }
      }
    }
  } else {
    float* of = (float*)outp + (size_t)b * NSEQ_ * D_;
#pragma unroll
    for (int i = 0; i < 4; ++i) {
      const int rl = wm * 64 + i * 16 + quad * 4;
#pragma unroll
      for (int j = 0; j < 4; ++j) {
        const int cl = wn * 64 + j * 16 + l16;
#pragma unroll
        for (int rr = 0; rr < 4; ++rr)
          __builtin_nontemporal_store(acc[i][j][rr],
                                      &of[(size_t)(M0 + rl + rr) * 1024 + (N0 + cl)]);
      }
    }
  }
}

// ---------------------------------------------------------------------------
extern "C" void kernel_launch(void* const* d_in, const int* in_sizes, int n_in,
                              void* d_out, int out_size, void* d_ws, size_t ws_size,
                              hipStream_t stream) {
  const float* x = (const float*)d_in[0];
  const float* wqr = (const float*)d_in[1];
  const float* wqi = (const float*)d_in[2];
  const float* wk = (const float*)d_in[3];
  const float* wv = (const float*)d_in[4];

  // workspace layout (all bf16 stored as short)
  short* wT = (short*)d_ws;                          // 4 * D*D            (8 MB)
  short* qb = wT + (size_t)4 * D_ * D_;              // BN * D             (64 MB)
  short* kT = qb + (size_t)BN_ * D_;                 // B * D * N          (64 MB)
  short* vT = kT + (size_t)BATCH_ * D_ * NSEQ_;      // B * D * N          (64 MB)
  short* kvT = vT + (size_t)BATCH_ * D_ * NSEQ_;     // B * D * D          (16 MB)
  float* ssk = (float*)(kvT + (size_t)BATCH_ * D_ * D_);  // B*D
  float* ssv = ssk + BATCH_ * D_;                    // B*D  (contiguous with ssk)
  float* invk = ssv + BATCH_ * D_;                   // B*D
  float* invv = invk + BATCH_ * D_;                  // B*D  (contiguous with invk)

  // bf16 x parked in d_out (128 MB fp32 buffer; only written by the final
  // GEMM, which runs strictly after x's last use)
  short* xb = (short*)d_out;

  hipMemsetAsync(ssk, 0, (size_t)2 * BATCH_ * D_ * sizeof(float), stream);

  // x fp32 -> bf16 : 33.5M elems / 8 per thread / 256 per block
  convert_x<<<dim3(16384), 256, 0, stream>>>(x, xb);

  transpose_convert_w<<<dim3(32, 32, 4), dim3(32, 8), 0, stream>>>(wqr, wqi, wk, wv, wT);

  // all four x@W GEMMs as one 256x256-tile phased GEMM over interleaved W
  gemm_x4w<<<dim3(2048), 512, 0, stream>>>(xb, wT, qb, kT, vT, ssk, ssv);

  finish_norms<<<dim3(64), 256, 0, stream>>>(ssk, invk);

  // kv^T[b][e][d] = relu( (sum_n V[n,e]K[n,d]) * invv[e] * invk[d] )
  gemm_bt<<<dim3(8, 8, 8), 256, 0, stream>>>(
      vT, kT, (size_t)D_ * NSEQ_, (size_t)D_ * NSEQ_, 4096, 0, invv, invk, (void*)kvT);

  // out[b][n][e] = sum_d query[n,d] * kv^T[e,d]   (fp32)
  gemm_bt<<<dim3(8, 32, 8), 256, 0, stream>>>(
      qb, kvT, (size_t)NSEQ_ * D_, (size_t)D_ * D_, 1024, 1, nullptr, nullptr, d_out);
}

// Round 4
// 689.629 us; speedup vs baseline: 1.1290x; 1.0551x over previous
//
#include <hip/hip_runtime.h>
#include <stdint.h>
#include <stddef.h>

// Problem constants: B=8, N=4096, D=1024
#define D_ 1024
#define NSEQ_ 4096
#define BATCH_ 8
#define BN_ (BATCH_ * NSEQ_)

typedef __attribute__((ext_vector_type(8))) short short8;
typedef __attribute__((ext_vector_type(4))) short short4_t;
typedef __attribute__((ext_vector_type(4))) float float4_t;

__device__ __forceinline__ short f2b(float f) {  // fp32 -> bf16 bits, RNE
  union { float f; uint32_t u; } x; x.f = f;
  uint32_t r = x.u + 0x7fffu + ((x.u >> 16) & 1u);
  return (short)(r >> 16);
}
__device__ __forceinline__ float b2f(short s) {
  union { float f; uint32_t u; } x; x.u = ((uint32_t)(uint16_t)s) << 16; return x.f;
}

// async global->LDS, 16B per lane; LDS dest is wave-uniform base + lane*16
__device__ __forceinline__ void gll16(const void* g, void* l) {
  auto gp = reinterpret_cast<const uint32_t __attribute__((address_space(1)))*>(
      reinterpret_cast<uintptr_t>(g));
  auto lp = reinterpret_cast<uint32_t __attribute__((address_space(3)))*>(
      reinterpret_cast<uintptr_t>(l));
  __builtin_amdgcn_global_load_lds(gp, lp, 16, 0, 0);
}

#define MFMA16(a, b, c) __builtin_amdgcn_mfma_f32_16x16x32_bf16(a, b, c, 0, 0, 0)

// ---------------------------------------------------------------------------
// Kernel A: x fp32 -> bf16 (memory-bound, 8 elems/thread). X read once ->
// non-temporal loads.
// ---------------------------------------------------------------------------
__global__ void convert_x(const float* __restrict__ X, short* __restrict__ Xb) {
  const size_t i = (size_t)blockIdx.x * 256 + threadIdx.x;  // 8 elems each
  const float4_t* p = (const float4_t*)(X + i * 8);
  float4_t a = __builtin_nontemporal_load(p);
  float4_t b = __builtin_nontemporal_load(p + 1);
  short8 o;
  o[0] = f2b(a.x); o[1] = f2b(a.y); o[2] = f2b(a.z); o[3] = f2b(a.w);
  o[4] = f2b(b.x); o[5] = f2b(b.y); o[6] = f2b(b.z); o[7] = f2b(b.w);
  *(short8*)(Xb + i * 8) = o;
}

// ---------------------------------------------------------------------------
// Kernel 0: weights (D,D) fp32 -> transposed bf16, INTERLEAVED layout:
//   Wint[(e>>4)*64 + z*16 + (e&15)][d] = W_z[d][e]
// ---------------------------------------------------------------------------
__global__ void transpose_convert_w(const float* __restrict__ w0, const float* __restrict__ w1,
                                    const float* __restrict__ w2, const float* __restrict__ w3,
                                    short* __restrict__ wT) {
  __shared__ float tile[32][33];
  const int z = blockIdx.z;
  const float* src = (z == 0) ? w0 : (z == 1) ? w1 : (z == 2) ? w2 : w3;
  const int d0 = blockIdx.y * 32, e0 = blockIdx.x * 32;
  const int tx = threadIdx.x, ty = threadIdx.y;
#pragma unroll
  for (int i = 0; i < 4; ++i) {
    int d = ty + i * 8;
    tile[d][tx] = __builtin_nontemporal_load(&src[(size_t)(d0 + d) * D_ + (e0 + tx)]);
  }
  __syncthreads();
#pragma unroll
  for (int i = 0; i < 4; ++i) {
    int e = ty + i * 8;
    const int eg = e0 + e;
    const int row = ((eg >> 4) << 6) + (z << 4) + (eg & 15);
    wT[(size_t)row * D_ + (d0 + tx)] = f2b(tile[tx][e]);
  }
}

// ---------------------------------------------------------------------------
// Kernel 1: QUAD-weight GEMM, 256x256 phased (see R2 notes). Round-2 block
// mapping restored (measured faster than R3's L2 chunking; HBM not binding).
// ---------------------------------------------------------------------------
__global__ __launch_bounds__(512, 2) void gemm_x4w(
    const short* __restrict__ Xb, const short* __restrict__ Wint,
    short* __restrict__ qout, short* __restrict__ kT, short* __restrict__ vT,
    float* __restrict__ ssk, float* __restrict__ ssv) {
  __shared__ short ring[4 * 16384];  // 128 KB; epilogue reuses front as 64x264

  const int t = threadIdx.x;
  const int w = t >> 6;
  const int lane = t & 63;
  const int l16 = lane & 15;
  const int quad = lane >> 4;
  const int wm = w >> 2;
  const int wn = w & 3;

  // XCD-aware bijective swizzle (2048 blocks % 8 == 0) — round-2 mapping
  const int bid = blockIdx.x;
  const int lin = (bid & 7) * 256 + (bid >> 3);
  const int mt = lin >> 4;
  const int nt = lin & 15;
  const int M0 = mt * 256;
  const int N0 = nt * 256;
  const int E0 = nt * 64;

  const float4_t fz = {0.f, 0.f, 0.f, 0.f};
  float4_t acc[8][4];
#pragma unroll
  for (int i = 0; i < 8; ++i)
#pragma unroll
    for (int j2 = 0; j2 < 4; ++j2) acc[i][j2] = fz;

  size_t goffA[2], goffB[2];
  int ldsu[2];
#pragma unroll
  for (int r = 0; r < 2; ++r) {
    const int uu = w * 2 + r;
    const int row = uu * 16 + (lane >> 2);
    const int sp = (lane & 3) ^ ((row >> 1) & 3);
    goffA[r] = (size_t)(M0 + row) * 1024 + sp * 8;
    goffB[r] = (size_t)(N0 + row) * 1024 + sp * 8;
    ldsu[r] = uu * 512;
  }
  int aoff[8], boff[4];
#pragma unroll
  for (int i = 0; i < 8; ++i) {
    const int row = wm * 128 + i * 16 + l16;
    aoff[i] = row * 32 + ((quad ^ ((row >> 1) & 3)) << 3);
  }
#pragma unroll
  for (int j2 = 0; j2 < 4; ++j2) {
    const int row = wn * 64 + j2 * 16 + l16;
    boff[j2] = row * 32 + ((quad ^ ((row >> 1) & 3)) << 3);
  }

  // prologue: stage steps 0,1
#pragma unroll
  for (int r = 0; r < 2; ++r) gll16(Xb + goffA[r], ring + ldsu[r]);
#pragma unroll
  for (int r = 0; r < 2; ++r) gll16(Wint + goffB[r], ring + 8192 + ldsu[r]);
#pragma unroll
  for (int r = 0; r < 2; ++r) gll16(Xb + goffA[r] + 32, ring + 16384 + ldsu[r]);
#pragma unroll
  for (int r = 0; r < 2; ++r) gll16(Wint + goffB[r] + 32, ring + 16384 + 8192 + ldsu[r]);
  asm volatile("s_waitcnt vmcnt(4)" ::: "memory");
  __builtin_amdgcn_s_barrier();

#pragma unroll 1
  for (int tt = 0; tt < 32; ++tt) {
    const short* As = ring + (tt & 3) * 16384;
    const short* Bs = As + 8192;
    short8 aF[8], bF[4];

    // phase A
#pragma unroll
    for (int i = 0; i < 4; ++i) aF[i] = *(const short8*)&As[aoff[i]];
#pragma unroll
    for (int j2 = 0; j2 < 4; ++j2) bF[j2] = *(const short8*)&Bs[boff[j2]];
    if (tt < 30) {
      short* dA = ring + ((tt + 2) & 3) * 16384;
      const int k0 = (tt + 2) * 32;
#pragma unroll
      for (int r = 0; r < 2; ++r) gll16(Xb + goffA[r] + k0, dA + ldsu[r]);
    }
    __builtin_amdgcn_s_barrier();
    asm volatile("s_waitcnt lgkmcnt(0)" ::: "memory");
    __builtin_amdgcn_s_setprio(1);
#pragma unroll
    for (int i = 0; i < 4; ++i)
#pragma unroll
      for (int j2 = 0; j2 < 4; ++j2) acc[i][j2] = MFMA16(aF[i], bF[j2], acc[i][j2]);
    __builtin_amdgcn_s_setprio(0);
    __builtin_amdgcn_s_barrier();

    // phase B
#pragma unroll
    for (int i = 4; i < 8; ++i) aF[i] = *(const short8*)&As[aoff[i]];
    if (tt < 30) {
      short* dB = ring + ((tt + 2) & 3) * 16384 + 8192;
      const int k0 = (tt + 2) * 32;
#pragma unroll
      for (int r = 0; r < 2; ++r) gll16(Wint + goffB[r] + k0, dB + ldsu[r]);
    }
    __builtin_amdgcn_s_barrier();
    asm volatile("s_waitcnt lgkmcnt(0)" ::: "memory");
    __builtin_amdgcn_s_setprio(1);
#pragma unroll
    for (int i = 4; i < 8; ++i)
#pragma unroll
      for (int j2 = 0; j2 < 4; ++j2) acc[i][j2] = MFMA16(aF[i], bF[j2], acc[i][j2]);
    __builtin_amdgcn_s_setprio(0);
    if (tt < 30) {
      asm volatile("s_waitcnt vmcnt(4)" ::: "memory");
    } else if (tt == 30) {
      asm volatile("s_waitcnt vmcnt(0)" ::: "memory");
    }
    __builtin_amdgcn_s_barrier();
  }

  // epilogue 1: query = relu*relu -> bf16 [bn][e]
  const int e = E0 + wn * 16 + l16;
#pragma unroll
  for (int i = 0; i < 8; ++i) {
    const int rowg = M0 + wm * 128 + i * 16 + quad * 4;
#pragma unroll
    for (int rr = 0; rr < 4; ++rr) {
      float v = fmaxf(acc[i][0][rr], 0.f) * fmaxf(acc[i][1][rr], 0.f);
      qout[(size_t)(rowg + rr) * 1024 + e] = f2b(v);
    }
  }

  // epilogue 2: k,v transposed -> [b][e][n] + sumsq
  short* T = ring;
  const int b = M0 >> 12;
  const int n0 = M0 & 4095;
#pragma unroll
  for (int wt = 2; wt < 4; ++wt) {
    short* dst = (wt == 2) ? kT : vT;
    float* ss = (wt == 2) ? ssk : ssv;
    __syncthreads();
#pragma unroll
    for (int i = 0; i < 8; ++i) {
      const int nl = wm * 128 + i * 16 + quad * 4;
      const int el = wn * 16 + l16;
      short4_t pk;
#pragma unroll
      for (int rr = 0; rr < 4; ++rr) pk[rr] = f2b(acc[i][wt][rr]);
      *(short4_t*)&T[el * 264 + nl] = pk;
    }
    __syncthreads();
#pragma unroll
    for (int it = 0; it < 4; ++it) {
      const int ee = it * 16 + (t >> 5);
      const int nch = (t & 31) * 8;
      short8 vv = *(const short8*)&T[ee * 264 + nch];
      *(short8*)&dst[((size_t)b * 1024 + E0 + ee) * 4096 + n0 + nch] = vv;
      float s = 0.f;
#pragma unroll
      for (int x2 = 0; x2 < 8; ++x2) { float f = b2f(vv[x2]); s += f * f; }
      s += __shfl_xor(s, 1, 32);
      s += __shfl_xor(s, 2, 32);
      s += __shfl_xor(s, 4, 32);
      s += __shfl_xor(s, 8, 32);
      s += __shfl_xor(s, 16, 32);
      if ((t & 31) == 0) atomicAdd(&ss[b * 1024 + E0 + ee], s);
    }
  }
}

// ---------------------------------------------------------------------------
// Kernel 2: inv norms
// ---------------------------------------------------------------------------
__global__ void finish_norms(const float* __restrict__ ss, float* __restrict__ inv) {
  const int i = blockIdx.x * 256 + threadIdx.x;
  if (i < 2 * BATCH_ * D_) inv[i] = 1.f / (sqrtf(ss[i]) + 1e-5f);
}

// ---------------------------------------------------------------------------
// Kernel 3 (NEW): phased batched gemm_bt_p: C[m][n] = sum_k A[m][k]*B[n][k].
// Tile 128m x 256n, BK=32, 512 thr = 8 waves (2M x 4N), wave tile 64x64
// (4x4 frags, 16 MFMA / K-step / wave). LDS: 4-slot ring x 24 KB (A 8KB +
// B 16KB) = 96 KB. Same counted-vmcnt phase schedule as gemm_x4w:
//   per K-step: {8 ds_read | 3 gll stage(t+2) | bar | lgkm0 | 16 MFMA |
//                vmcnt(3) | bar}
// Staging: 24 gll units of 1KB (16 rows x 64B); wave w owns units 3w..3w+2
// (u<8 -> A rows, u>=8 -> B rows). Per-wave FIFO: 6 outstanding, wait to 3.
// Both-sides XOR swizzle on k-slot as in gemm_x4w.
// mode 0: out bf16 = relu(C * rs[m] * cs[n])   (kv^T epilogue)
// mode 1: out fp32 = C, non-temporal            (final output)
// ---------------------------------------------------------------------------
__global__ __launch_bounds__(512, 2) void gemm_bt_p(
    const short* __restrict__ A, const short* __restrict__ Bm,
    size_t sAb, size_t sBb, int K, int mode,
    const float* __restrict__ rsb, const float* __restrict__ csb,
    void* __restrict__ outp) {
  __shared__ short ring[4 * 12288];  // 96 KB

  const int t = threadIdx.x;
  const int w = t >> 6;
  const int lane = t & 63;
  const int l16 = lane & 15;
  const int quad = lane >> 4;
  const int wm = w >> 2;       // 0..1 : 64-row half of A-tile
  const int wn = w & 3;        // 0..3 : 64-row quarter of B-tile
  const int M0 = blockIdx.y * 128, N0 = blockIdx.x * 256, b = blockIdx.z;
  const short* Ab = A + (size_t)b * sAb;
  const short* Bb = Bm + (size_t)b * sBb;
  const int NT = K >> 5;

  const float4_t fz = {0.f, 0.f, 0.f, 0.f};
  float4_t acc[4][4];
#pragma unroll
  for (int i = 0; i < 4; ++i)
#pragma unroll
    for (int j = 0; j < 4; ++j) acc[i][j] = fz;

  // staging units: wave w owns u = 3w..3w+2; u<8 A, u>=8 B
  const short* gptr[3];
  int ldso[3];
#pragma unroll
  for (int r = 0; r < 3; ++r) {
    const int u = w * 3 + r;
    const int lrow = (u < 8 ? u * 16 : (u - 8) * 16) + (lane >> 2);
    const int sp = (lane & 3) ^ ((lrow >> 1) & 3);
    gptr[r] = (u < 8 ? Ab + (size_t)(M0 + lrow) * K : Bb + (size_t)(N0 + lrow) * K) + sp * 8;
    ldso[r] = (u < 8 ? u * 512 : 4096 + (u - 8) * 512);
  }
  // ds_read offsets (shorts), swizzled to match
  int aoff[4], boff[4];
#pragma unroll
  for (int i = 0; i < 4; ++i) {
    const int row = wm * 64 + i * 16 + l16;
    aoff[i] = row * 32 + ((quad ^ ((row >> 1) & 3)) << 3);
  }
#pragma unroll
  for (int j = 0; j < 4; ++j) {
    const int row = wn * 64 + j * 16 + l16;
    boff[j] = 4096 + row * 32 + ((quad ^ ((row >> 1) & 3)) << 3);
  }

  // prologue: stage steps 0,1 (6 gll/lane in flight)
#pragma unroll
  for (int r = 0; r < 3; ++r) gll16(gptr[r], ring + ldso[r]);
#pragma unroll
  for (int r = 0; r < 3; ++r) gll16(gptr[r] + 32, ring + 12288 + ldso[r]);
  asm volatile("s_waitcnt vmcnt(3)" ::: "memory");  // slot 0 landed
  __builtin_amdgcn_s_barrier();

#pragma unroll 1
  for (int tt = 0; tt < NT; ++tt) {
    const short* As = ring + (tt & 3) * 12288;
    short8 aF[4], bF[4];
#pragma unroll
    for (int i = 0; i < 4; ++i) aF[i] = *(const short8*)&As[aoff[i]];
#pragma unroll
    for (int j = 0; j < 4; ++j) bF[j] = *(const short8*)&As[boff[j]];
    if (tt < NT - 2) {
      short* dS = ring + ((tt + 2) & 3) * 12288;
      const int k0 = (tt + 2) * 32;
#pragma unroll
      for (int r = 0; r < 3; ++r) gll16(gptr[r] + k0, dS + ldso[r]);
    }
    __builtin_amdgcn_s_barrier();
    asm volatile("s_waitcnt lgkmcnt(0)" ::: "memory");
    __builtin_amdgcn_s_setprio(1);
#pragma unroll
    for (int i = 0; i < 4; ++i)
#pragma unroll
      for (int j = 0; j < 4; ++j) acc[i][j] = MFMA16(aF[i], bF[j], acc[i][j]);
    __builtin_amdgcn_s_setprio(0);
    if (tt < NT - 2) {
      asm volatile("s_waitcnt vmcnt(3)" ::: "memory");  // this step's 3 may fly
    } else if (tt == NT - 2) {
      asm volatile("s_waitcnt vmcnt(0)" ::: "memory");  // final drain
    }
    __builtin_amdgcn_s_barrier();
  }

  if (mode == 0) {
    short* ob = (short*)outp + (size_t)b * D_ * D_;
    const float* rs = rsb + b * D_ + M0;
    const float* cs = csb + b * D_ + N0;
#pragma unroll
    for (int i = 0; i < 4; ++i) {
      const int rl = wm * 64 + i * 16 + quad * 4;
#pragma unroll
      for (int j = 0; j < 4; ++j) {
        const int cl = wn * 64 + j * 16 + l16;
        const float csc = cs[cl];
#pragma unroll
        for (int rr = 0; rr < 4; ++rr) {
          float v = acc[i][j][rr] * rs[rl + rr] * csc;
          v = fmaxf(v, 0.f);
          ob[(size_t)(M0 + rl + rr) * 1024 + (N0 + cl)] = f2b(v);
        }
      }
    }
  } else {
    float* of = (float*)outp + (size_t)b * NSEQ_ * D_;
#pragma unroll
    for (int i = 0; i < 4; ++i) {
      const int rl = wm * 64 + i * 16 + quad * 4;
#pragma unroll
      for (int j = 0; j < 4; ++j) {
        const int cl = wn * 64 + j * 16 + l16;
#pragma unroll
        for (int rr = 0; rr < 4; ++rr)
          __builtin_nontemporal_store(acc[i][j][rr],
                                      &of[(size_t)(M0 + rl + rr) * 1024 + (N0 + cl)]);
      }
    }
  }
}

// ---------------------------------------------------------------------------
extern "C" void kernel_launch(void* const* d_in, const int* in_sizes, int n_in,
                              void* d_out, int out_size, void* d_ws, size_t ws_size,
                              hipStream_t stream) {
  const float* x = (const float*)d_in[0];
  const float* wqr = (const float*)d_in[1];
  const float* wqi = (const float*)d_in[2];
  const float* wk = (const float*)d_in[3];
  const float* wv = (const float*)d_in[4];

  // workspace layout (all bf16 stored as short)
  short* wT = (short*)d_ws;                          // 4 * D*D            (8 MB)
  short* qb = wT + (size_t)4 * D_ * D_;              // BN * D             (64 MB)
  short* kT = qb + (size_t)BN_ * D_;                 // B * D * N          (64 MB)
  short* vT = kT + (size_t)BATCH_ * D_ * NSEQ_;      // B * D * N          (64 MB)
  short* kvT = vT + (size_t)BATCH_ * D_ * NSEQ_;     // B * D * D          (16 MB)
  float* ssk = (float*)(kvT + (size_t)BATCH_ * D_ * D_);  // B*D
  float* ssv = ssk + BATCH_ * D_;                    // B*D
  float* invk = ssv + BATCH_ * D_;                   // B*D
  float* invv = invk + BATCH_ * D_;                  // B*D

  // bf16 x parked in d_out (only overwritten by the final GEMM, which runs
  // strictly after x's last use)
  short* xb = (short*)d_out;

  hipMemsetAsync(ssk, 0, (size_t)2 * BATCH_ * D_ * sizeof(float), stream);

  convert_x<<<dim3(16384), 256, 0, stream>>>(x, xb);

  transpose_convert_w<<<dim3(32, 32, 4), dim3(32, 8), 0, stream>>>(wqr, wqi, wk, wv, wT);

  gemm_x4w<<<dim3(2048), 512, 0, stream>>>(xb, wT, qb, kT, vT, ssk, ssv);

  finish_norms<<<dim3(64), 256, 0, stream>>>(ssk, invk);

  // kv^T[b][e][d] = relu( (sum_n V[n,e]K[n,d]) * invv[e] * invk[d] )
  // M = e (1024, 8 tiles of 128), N = d (1024, 4 tiles of 256), K = 4096
  gemm_bt_p<<<dim3(4, 8, 8), 512, 0, stream>>>(
      vT, kT, (size_t)D_ * NSEQ_, (size_t)D_ * NSEQ_, 4096, 0, invv, invk, (void*)kvT);

  // out[b][n][e] = sum_d query[n,d] * kv^T[e,d]   (fp32)
  // M = n (4096, 32 tiles of 128), N = e (1024, 4 tiles of 256), K = 1024
  gemm_bt_p<<<dim3(4, 32, 8), 512, 0, stream>>>(
      qb, kvT, (size_t)NSEQ_ * D_, (size_t)D_ * D_, 1024, 1, nullptr, nullptr, d_out);
}

// Round 5
// 687.642 us; speedup vs baseline: 1.1322x; 1.0029x over previous
//
#include <hip/hip_runtime.h>
#include <stdint.h>
#include <stddef.h>

// Problem constants: B=8, N=4096, D=1024
#define D_ 1024
#define NSEQ_ 4096
#define BATCH_ 8
#define BN_ (BATCH_ * NSEQ_)

typedef __attribute__((ext_vector_type(8))) short short8;
typedef __attribute__((ext_vector_type(4))) short short4_t;
typedef __attribute__((ext_vector_type(4))) float float4_t;

__device__ __forceinline__ short f2b(float f) {  // fp32 -> bf16 bits, RNE
  union { float f; uint32_t u; } x; x.f = f;
  uint32_t r = x.u + 0x7fffu + ((x.u >> 16) & 1u);
  return (short)(r >> 16);
}
__device__ __forceinline__ float b2f(short s) {
  union { float f; uint32_t u; } x; x.u = ((uint32_t)(uint16_t)s) << 16; return x.f;
}

// async global->LDS, 16B per lane; LDS dest is wave-uniform base + lane*16
__device__ __forceinline__ void gll16(const void* g, void* l) {
  auto gp = reinterpret_cast<const uint32_t __attribute__((address_space(1)))*>(
      reinterpret_cast<uintptr_t>(g));
  auto lp = reinterpret_cast<uint32_t __attribute__((address_space(3)))*>(
      reinterpret_cast<uintptr_t>(l));
  __builtin_amdgcn_global_load_lds(gp, lp, 16, 0, 0);
}

#define MFMA16(a, b, c) __builtin_amdgcn_mfma_f32_16x16x32_bf16(a, b, c, 0, 0, 0)

// ---------------------------------------------------------------------------
// Kernel A: x fp32 -> bf16 (memory-bound, 8 elems/thread). X read once ->
// non-temporal loads.
// ---------------------------------------------------------------------------
__global__ void convert_x(const float* __restrict__ X, short* __restrict__ Xb) {
  const size_t i = (size_t)blockIdx.x * 256 + threadIdx.x;  // 8 elems each
  const float4_t* p = (const float4_t*)(X + i * 8);
  float4_t a = __builtin_nontemporal_load(p);
  float4_t b = __builtin_nontemporal_load(p + 1);
  short8 o;
  o[0] = f2b(a.x); o[1] = f2b(a.y); o[2] = f2b(a.z); o[3] = f2b(a.w);
  o[4] = f2b(b.x); o[5] = f2b(b.y); o[6] = f2b(b.z); o[7] = f2b(b.w);
  *(short8*)(Xb + i * 8) = o;
}

// ---------------------------------------------------------------------------
// Kernel 0: weights (D,D) fp32 -> transposed bf16, INTERLEAVED layout:
//   Wint[(e>>4)*64 + z*16 + (e&15)][d] = W_z[d][e]
// ---------------------------------------------------------------------------
__global__ void transpose_convert_w(const float* __restrict__ w0, const float* __restrict__ w1,
                                    const float* __restrict__ w2, const float* __restrict__ w3,
                                    short* __restrict__ wT) {
  __shared__ float tile[32][33];
  const int z = blockIdx.z;
  const float* src = (z == 0) ? w0 : (z == 1) ? w1 : (z == 2) ? w2 : w3;
  const int d0 = blockIdx.y * 32, e0 = blockIdx.x * 32;
  const int tx = threadIdx.x, ty = threadIdx.y;
#pragma unroll
  for (int i = 0; i < 4; ++i) {
    int d = ty + i * 8;
    tile[d][tx] = __builtin_nontemporal_load(&src[(size_t)(d0 + d) * D_ + (e0 + tx)]);
  }
  __syncthreads();
#pragma unroll
  for (int i = 0; i < 4; ++i) {
    int e = ty + i * 8;
    const int eg = e0 + e;
    const int row = ((eg >> 4) << 6) + (z << 4) + (eg & 15);
    wT[(size_t)row * D_ + (d0 + tx)] = f2b(tile[tx][e]);
  }
}

// ---------------------------------------------------------------------------
// Kernel 1: QUAD-weight GEMM, 256x256 phased.
// R5 change: prefetch distance 2 -> 3 steps (stage slot t+3 during step t;
// end-of-step wait vmcnt(8) = two steps' loads in flight). Issue->wait
// distance now ~2 K-steps (>= HBM latency ~900cyc) instead of ~1.
// Ring safety: slot (t+3)&3 == (t-1)&3, last read during step t-1; those
// ds_reads completed before the end-of-(t-1) barrier which precedes step t's
// staging. End-of-step-t vmcnt(8) guarantees slot t+1 (issued at t-2) landed.
// ---------------------------------------------------------------------------
__global__ __launch_bounds__(512, 2) void gemm_x4w(
    const short* __restrict__ Xb, const short* __restrict__ Wint,
    short* __restrict__ qout, short* __restrict__ kT, short* __restrict__ vT,
    float* __restrict__ ssk, float* __restrict__ ssv) {
  __shared__ short ring[4 * 16384];  // 128 KB; epilogue reuses front as 64x264

  const int t = threadIdx.x;
  const int w = t >> 6;
  const int lane = t & 63;
  const int l16 = lane & 15;
  const int quad = lane >> 4;
  const int wm = w >> 2;
  const int wn = w & 3;

  // XCD-aware bijective swizzle (2048 blocks % 8 == 0)
  const int bid = blockIdx.x;
  const int lin = (bid & 7) * 256 + (bid >> 3);
  const int mt = lin >> 4;
  const int nt = lin & 15;
  const int M0 = mt * 256;
  const int N0 = nt * 256;
  const int E0 = nt * 64;

  const float4_t fz = {0.f, 0.f, 0.f, 0.f};
  float4_t acc[8][4];
#pragma unroll
  for (int i = 0; i < 8; ++i)
#pragma unroll
    for (int j2 = 0; j2 < 4; ++j2) acc[i][j2] = fz;

  size_t goffA[2], goffB[2];
  int ldsu[2];
#pragma unroll
  for (int r = 0; r < 2; ++r) {
    const int uu = w * 2 + r;
    const int row = uu * 16 + (lane >> 2);
    const int sp = (lane & 3) ^ ((row >> 1) & 3);
    goffA[r] = (size_t)(M0 + row) * 1024 + sp * 8;
    goffB[r] = (size_t)(N0 + row) * 1024 + sp * 8;
    ldsu[r] = uu * 512;
  }
  int aoff[8], boff[4];
#pragma unroll
  for (int i = 0; i < 8; ++i) {
    const int row = wm * 128 + i * 16 + l16;
    aoff[i] = row * 32 + ((quad ^ ((row >> 1) & 3)) << 3);
  }
#pragma unroll
  for (int j2 = 0; j2 < 4; ++j2) {
    const int row = wn * 64 + j2 * 16 + l16;
    boff[j2] = row * 32 + ((quad ^ ((row >> 1) & 3)) << 3);
  }

  // prologue: stage slots 0,1,2 (12 gll/lane in flight)
#pragma unroll
  for (int s = 0; s < 3; ++s) {
#pragma unroll
    for (int r = 0; r < 2; ++r) gll16(Xb + goffA[r] + s * 32, ring + s * 16384 + ldsu[r]);
#pragma unroll
    for (int r = 0; r < 2; ++r) gll16(Wint + goffB[r] + s * 32, ring + s * 16384 + 8192 + ldsu[r]);
  }
  asm volatile("s_waitcnt vmcnt(8)" ::: "memory");  // slot 0 landed; 1,2 may fly
  __builtin_amdgcn_s_barrier();

#pragma unroll 1
  for (int tt = 0; tt < 32; ++tt) {
    const short* As = ring + (tt & 3) * 16384;
    const short* Bs = As + 8192;
    short8 aF[8], bF[4];

    // phase A: read a0..3+b0..3, stage A(tt+3)
#pragma unroll
    for (int i = 0; i < 4; ++i) aF[i] = *(const short8*)&As[aoff[i]];
#pragma unroll
    for (int j2 = 0; j2 < 4; ++j2) bF[j2] = *(const short8*)&Bs[boff[j2]];
    if (tt < 29) {
      short* dA = ring + ((tt + 3) & 3) * 16384;
      const int k0 = (tt + 3) * 32;
#pragma unroll
      for (int r = 0; r < 2; ++r) gll16(Xb + goffA[r] + k0, dA + ldsu[r]);
    }
    __builtin_amdgcn_s_barrier();
    asm volatile("s_waitcnt lgkmcnt(0)" ::: "memory");
    __builtin_amdgcn_s_setprio(1);
#pragma unroll
    for (int i = 0; i < 4; ++i)
#pragma unroll
      for (int j2 = 0; j2 < 4; ++j2) acc[i][j2] = MFMA16(aF[i], bF[j2], acc[i][j2]);
    __builtin_amdgcn_s_setprio(0);
    __builtin_amdgcn_s_barrier();

    // phase B: read a4..7, stage B(tt+3), counted vmcnt
#pragma unroll
    for (int i = 4; i < 8; ++i) aF[i] = *(const short8*)&As[aoff[i]];
    if (tt < 29) {
      short* dB = ring + ((tt + 3) & 3) * 16384 + 8192;
      const int k0 = (tt + 3) * 32;
#pragma unroll
      for (int r = 0; r < 2; ++r) gll16(Wint + goffB[r] + k0, dB + ldsu[r]);
    }
    __builtin_amdgcn_s_barrier();
    asm volatile("s_waitcnt lgkmcnt(0)" ::: "memory");
    __builtin_amdgcn_s_setprio(1);
#pragma unroll
    for (int i = 4; i < 8; ++i)
#pragma unroll
      for (int j2 = 0; j2 < 4; ++j2) acc[i][j2] = MFMA16(aF[i], bF[j2], acc[i][j2]);
    __builtin_amdgcn_s_setprio(0);
    if (tt < 29) {
      asm volatile("s_waitcnt vmcnt(8)" ::: "memory");  // 2 steps' loads may fly
    } else if (tt == 29) {
      asm volatile("s_waitcnt vmcnt(4)" ::: "memory");  // slot 31's 4 may fly
    } else if (tt == 30) {
      asm volatile("s_waitcnt vmcnt(0)" ::: "memory");  // final drain
    }
    __builtin_amdgcn_s_barrier();
  }

  // epilogue 1: query = relu*relu -> bf16 [bn][e]
  const int e = E0 + wn * 16 + l16;
#pragma unroll
  for (int i = 0; i < 8; ++i) {
    const int rowg = M0 + wm * 128 + i * 16 + quad * 4;
#pragma unroll
    for (int rr = 0; rr < 4; ++rr) {
      float v = fmaxf(acc[i][0][rr], 0.f) * fmaxf(acc[i][1][rr], 0.f);
      qout[(size_t)(rowg + rr) * 1024 + e] = f2b(v);
    }
  }

  // epilogue 2: k,v transposed -> [b][e][n] + sumsq
  short* T = ring;
  const int b = M0 >> 12;
  const int n0 = M0 & 4095;
#pragma unroll
  for (int wt = 2; wt < 4; ++wt) {
    short* dst = (wt == 2) ? kT : vT;
    float* ss = (wt == 2) ? ssk : ssv;
    __syncthreads();
#pragma unroll
    for (int i = 0; i < 8; ++i) {
      const int nl = wm * 128 + i * 16 + quad * 4;
      const int el = wn * 16 + l16;
      short4_t pk;
#pragma unroll
      for (int rr = 0; rr < 4; ++rr) pk[rr] = f2b(acc[i][wt][rr]);
      *(short4_t*)&T[el * 264 + nl] = pk;
    }
    __syncthreads();
#pragma unroll
    for (int it = 0; it < 4; ++it) {
      const int ee = it * 16 + (t >> 5);
      const int nch = (t & 31) * 8;
      short8 vv = *(const short8*)&T[ee * 264 + nch];
      *(short8*)&dst[((size_t)b * 1024 + E0 + ee) * 4096 + n0 + nch] = vv;
      float s = 0.f;
#pragma unroll
      for (int x2 = 0; x2 < 8; ++x2) { float f = b2f(vv[x2]); s += f * f; }
      s += __shfl_xor(s, 1, 32);
      s += __shfl_xor(s, 2, 32);
      s += __shfl_xor(s, 4, 32);
      s += __shfl_xor(s, 8, 32);
      s += __shfl_xor(s, 16, 32);
      if ((t & 31) == 0) atomicAdd(&ss[b * 1024 + E0 + ee], s);
    }
  }
}

// ---------------------------------------------------------------------------
// Kernel 2: inv norms
// ---------------------------------------------------------------------------
__global__ void finish_norms(const float* __restrict__ ss, float* __restrict__ inv) {
  const int i = blockIdx.x * 256 + threadIdx.x;
  if (i < 2 * BATCH_ * D_) inv[i] = 1.f / (sqrtf(ss[i]) + 1e-5f);
}

// ---------------------------------------------------------------------------
// Kernel 3: phased batched gemm_bt_p (128m x 256n, BK=32, 4-slot ring 96KB).
// R5: prefetch distance 3 (stage t+3, vmcnt(6) = 2 steps' loads in flight).
// mode 0: out bf16 = relu(C * rs[m] * cs[n]);  mode 1: out fp32 NT.
// ---------------------------------------------------------------------------
__global__ __launch_bounds__(512, 2) void gemm_bt_p(
    const short* __restrict__ A, const short* __restrict__ Bm,
    size_t sAb, size_t sBb, int K, int mode,
    const float* __restrict__ rsb, const float* __restrict__ csb,
    void* __restrict__ outp) {
  __shared__ short ring[4 * 12288];  // 96 KB

  const int t = threadIdx.x;
  const int w = t >> 6;
  const int lane = t & 63;
  const int l16 = lane & 15;
  const int quad = lane >> 4;
  const int wm = w >> 2;
  const int wn = w & 3;
  const int M0 = blockIdx.y * 128, N0 = blockIdx.x * 256, b = blockIdx.z;
  const short* Ab = A + (size_t)b * sAb;
  const short* Bb = Bm + (size_t)b * sBb;
  const int NT = K >> 5;

  const float4_t fz = {0.f, 0.f, 0.f, 0.f};
  float4_t acc[4][4];
#pragma unroll
  for (int i = 0; i < 4; ++i)
#pragma unroll
    for (int j = 0; j < 4; ++j) acc[i][j] = fz;

  // staging units: wave w owns u = 3w..3w+2; u<8 A, u>=8 B
  const short* gptr[3];
  int ldso[3];
#pragma unroll
  for (int r = 0; r < 3; ++r) {
    const int u = w * 3 + r;
    const int lrow = (u < 8 ? u * 16 : (u - 8) * 16) + (lane >> 2);
    const int sp = (lane & 3) ^ ((lrow >> 1) & 3);
    gptr[r] = (u < 8 ? Ab + (size_t)(M0 + lrow) * K : Bb + (size_t)(N0 + lrow) * K) + sp * 8;
    ldso[r] = (u < 8 ? u * 512 : 4096 + (u - 8) * 512);
  }
  int aoff[4], boff[4];
#pragma unroll
  for (int i = 0; i < 4; ++i) {
    const int row = wm * 64 + i * 16 + l16;
    aoff[i] = row * 32 + ((quad ^ ((row >> 1) & 3)) << 3);
  }
#pragma unroll
  for (int j = 0; j < 4; ++j) {
    const int row = wn * 64 + j * 16 + l16;
    boff[j] = 4096 + row * 32 + ((quad ^ ((row >> 1) & 3)) << 3);
  }

  // prologue: stage slots 0,1,2 (9 gll/lane in flight)
#pragma unroll
  for (int s = 0; s < 3; ++s)
#pragma unroll
    for (int r = 0; r < 3; ++r) gll16(gptr[r] + s * 32, ring + s * 12288 + ldso[r]);
  asm volatile("s_waitcnt vmcnt(6)" ::: "memory");  // slot 0 landed
  __builtin_amdgcn_s_barrier();

#pragma unroll 1
  for (int tt = 0; tt < NT; ++tt) {
    const short* As = ring + (tt & 3) * 12288;
    short8 aF[4], bF[4];
#pragma unroll
    for (int i = 0; i < 4; ++i) aF[i] = *(const short8*)&As[aoff[i]];
#pragma unroll
    for (int j = 0; j < 4; ++j) bF[j] = *(const short8*)&As[boff[j]];
    if (tt < NT - 3) {
      short* dS = ring + ((tt + 3) & 3) * 12288;
      const int k0 = (tt + 3) * 32;
#pragma unroll
      for (int r = 0; r < 3; ++r) gll16(gptr[r] + k0, dS + ldso[r]);
    }
    __builtin_amdgcn_s_barrier();
    asm volatile("s_waitcnt lgkmcnt(0)" ::: "memory");
    __builtin_amdgcn_s_setprio(1);
#pragma unroll
    for (int i = 0; i < 4; ++i)
#pragma unroll
      for (int j = 0; j < 4; ++j) acc[i][j] = MFMA16(aF[i], bF[j], acc[i][j]);
    __builtin_amdgcn_s_setprio(0);
    if (tt < NT - 3) {
      asm volatile("s_waitcnt vmcnt(6)" ::: "memory");  // 2 steps' loads may fly
    } else if (tt == NT - 3) {
      asm volatile("s_waitcnt vmcnt(3)" ::: "memory");
    } else if (tt == NT - 2) {
      asm volatile("s_waitcnt vmcnt(0)" ::: "memory");
    }
    __builtin_amdgcn_s_barrier();
  }

  if (mode == 0) {
    short* ob = (short*)outp + (size_t)b * D_ * D_;
    const float* rs = rsb + b * D_ + M0;
    const float* cs = csb + b * D_ + N0;
#pragma unroll
    for (int i = 0; i < 4; ++i) {
      const int rl = wm * 64 + i * 16 + quad * 4;
#pragma unroll
      for (int j = 0; j < 4; ++j) {
        const int cl = wn * 64 + j * 16 + l16;
        const float csc = cs[cl];
#pragma unroll
        for (int rr = 0; rr < 4; ++rr) {
          float v = acc[i][j][rr] * rs[rl + rr] * csc;
          v = fmaxf(v, 0.f);
          ob[(size_t)(M0 + rl + rr) * 1024 + (N0 + cl)] = f2b(v);
        }
      }
    }
  } else {
    float* of = (float*)outp + (size_t)b * NSEQ_ * D_;
#pragma unroll
    for (int i = 0; i < 4; ++i) {
      const int rl = wm * 64 + i * 16 + quad * 4;
#pragma unroll
      for (int j = 0; j < 4; ++j) {
        const int cl = wn * 64 + j * 16 + l16;
#pragma unroll
        for (int rr = 0; rr < 4; ++rr)
          __builtin_nontemporal_store(acc[i][j][rr],
                                      &of[(size_t)(M0 + rl + rr) * 1024 + (N0 + cl)]);
      }
    }
  }
}

// ---------------------------------------------------------------------------
extern "C" void kernel_launch(void* const* d_in, const int* in_sizes, int n_in,
                              void* d_out, int out_size, void* d_ws, size_t ws_size,
                              hipStream_t stream) {
  const float* x = (const float*)d_in[0];
  const float* wqr = (const float*)d_in[1];
  const float* wqi = (const float*)d_in[2];
  const float* wk = (const float*)d_in[3];
  const float* wv = (const float*)d_in[4];

  // workspace layout (all bf16 stored as short)
  short* wT = (short*)d_ws;                          // 4 * D*D            (8 MB)
  short* qb = wT + (size_t)4 * D_ * D_;              // BN * D             (64 MB)
  short* kT = qb + (size_t)BN_ * D_;                 // B * D * N          (64 MB)
  short* vT = kT + (size_t)BATCH_ * D_ * NSEQ_;      // B * D * N          (64 MB)
  short* kvT = vT + (size_t)BATCH_ * D_ * NSEQ_;     // B * D * D          (16 MB)
  float* ssk = (float*)(kvT + (size_t)BATCH_ * D_ * D_);  // B*D
  float* ssv = ssk + BATCH_ * D_;                    // B*D
  float* invk = ssv + BATCH_ * D_;                   // B*D
  float* invv = invk + BATCH_ * D_;                  // B*D

  // bf16 x parked in d_out (only overwritten by the final GEMM, which runs
  // strictly after x's last use)
  short* xb = (short*)d_out;

  hipMemsetAsync(ssk, 0, (size_t)2 * BATCH_ * D_ * sizeof(float), stream);

  convert_x<<<dim3(16384), 256, 0, stream>>>(x, xb);

  transpose_convert_w<<<dim3(32, 32, 4), dim3(32, 8), 0, stream>>>(wqr, wqi, wk, wv, wT);

  gemm_x4w<<<dim3(2048), 512, 0, stream>>>(xb, wT, qb, kT, vT, ssk, ssv);

  finish_norms<<<dim3(64), 256, 0, stream>>>(ssk, invk);

  // kv^T[b][e][d] = relu( (sum_n V[n,e]K[n,d]) * invv[e] * invk[d] )
  gemm_bt_p<<<dim3(4, 8, 8), 512, 0, stream>>>(
      vT, kT, (size_t)D_ * NSEQ_, (size_t)D_ * NSEQ_, 4096, 0, invv, invk, (void*)kvT);

  // out[b][n][e] = sum_d query[n,d] * kv^T[e,d]   (fp32)
  gemm_bt_p<<<dim3(4, 32, 8), 512, 0, stream>>>(
      qb, kvT, (size_t)NSEQ_ * D_, (size_t)D_ * D_, 1024, 1, nullptr, nullptr, d_out);
}

// Round 6
// 674.348 us; speedup vs baseline: 1.1545x; 1.0197x over previous
//
#include <hip/hip_runtime.h>
#include <stdint.h>
#include <stddef.h>

// Problem constants: B=8, N=4096, D=1024
#define D_ 1024
#define NSEQ_ 4096
#define BATCH_ 8
#define BN_ (BATCH_ * NSEQ_)

typedef __attribute__((ext_vector_type(8))) short short8;
typedef __attribute__((ext_vector_type(4))) short short4_t;
typedef __attribute__((ext_vector_type(4))) float float4_t;

__device__ __forceinline__ short f2b(float f) {  // fp32 -> bf16 bits, RNE
  union { float f; uint32_t u; } x; x.f = f;
  uint32_t r = x.u + 0x7fffu + ((x.u >> 16) & 1u);
  return (short)(r >> 16);
}
__device__ __forceinline__ float b2f(short s) {
  union { float f; uint32_t u; } x; x.u = ((uint32_t)(uint16_t)s) << 16; return x.f;
}

// async global->LDS, 16B per lane; LDS dest is wave-uniform base + lane*16
__device__ __forceinline__ void gll16(const void* g, void* l) {
  auto gp = reinterpret_cast<const uint32_t __attribute__((address_space(1)))*>(
      reinterpret_cast<uintptr_t>(g));
  auto lp = reinterpret_cast<uint32_t __attribute__((address_space(3)))*>(
      reinterpret_cast<uintptr_t>(l));
  __builtin_amdgcn_global_load_lds(gp, lp, 16, 0, 0);
}

#define MFMA16(a, b, c) __builtin_amdgcn_mfma_f32_16x16x32_bf16(a, b, c, 0, 0, 0)

// ---------------------------------------------------------------------------
// Kernel A: x fp32 -> bf16 (memory-bound). X read once -> non-temporal loads.
// ---------------------------------------------------------------------------
__global__ void convert_x(const float* __restrict__ X, short* __restrict__ Xb) {
  const size_t i = (size_t)blockIdx.x * 256 + threadIdx.x;  // 8 elems each
  const float4_t* p = (const float4_t*)(X + i * 8);
  float4_t a = __builtin_nontemporal_load(p);
  float4_t b = __builtin_nontemporal_load(p + 1);
  short8 o;
  o[0] = f2b(a.x); o[1] = f2b(a.y); o[2] = f2b(a.z); o[3] = f2b(a.w);
  o[4] = f2b(b.x); o[5] = f2b(b.y); o[6] = f2b(b.z); o[7] = f2b(b.w);
  *(short8*)(Xb + i * 8) = o;
}

// ---------------------------------------------------------------------------
// Kernel 0: weights (D,D) fp32 -> transposed bf16, INTERLEAVED layout:
//   Wint[(e>>4)*64 + z*16 + (e&15)][d] = W_z[d][e]
// ---------------------------------------------------------------------------
__global__ void transpose_convert_w(const float* __restrict__ w0, const float* __restrict__ w1,
                                    const float* __restrict__ w2, const float* __restrict__ w3,
                                    short* __restrict__ wT) {
  __shared__ float tile[32][33];
  const int z = blockIdx.z;
  const float* src = (z == 0) ? w0 : (z == 1) ? w1 : (z == 2) ? w2 : w3;
  const int d0 = blockIdx.y * 32, e0 = blockIdx.x * 32;
  const int tx = threadIdx.x, ty = threadIdx.y;
#pragma unroll
  for (int i = 0; i < 4; ++i) {
    int d = ty + i * 8;
    tile[d][tx] = __builtin_nontemporal_load(&src[(size_t)(d0 + d) * D_ + (e0 + tx)]);
  }
  __syncthreads();
#pragma unroll
  for (int i = 0; i < 4; ++i) {
    int e = ty + i * 8;
    const int eg = e0 + e;
    const int row = ((eg >> 4) << 6) + (z << 4) + (eg & 15);
    wT[(size_t)row * D_ + (d0 + tx)] = f2b(tile[tx][e]);
  }
}

// ---------------------------------------------------------------------------
// Kernel 1: QUAD-weight GEMM, 256x256, BK=32, 4-slot ring.
// R6: read-ahead-one-step schedule. Per K-step t:
//   vmcnt(4)  -> my slot-(t+1) staging (issued at t-2) landed
//   s_barrier -> ALL waves' slot-(t+1) staging landed; all MFMA(t-1) done
//   issue reads(t+1) into frag buffer (t+1)&1   [LDS pipe works under MFMAs]
//   issue stage(t+3)                            [slot (t-1)&3: hard-safe]
//   MFMA(t) on frag buffer t&1  [compiler inserts counted lgkm wait; reads(t)
//                                were issued a full step ago -> no stall]
// NO forced lgkmcnt(0): the old schedule serialized the DS pipe (1150 cyc/
// step) with the MFMA pipe (1240 cyc/step) -> 2900 cyc/step measured. This
// overlaps them -> target ~1600-1900 cyc/step.
// ---------------------------------------------------------------------------
#define X4W_STEP(TT, AC, BC, AN, BN2)                                          \
  {                                                                            \
    const int tt_ = (TT);                                                      \
    if (tt_ < 30) { asm volatile("s_waitcnt vmcnt(4)" ::: "memory"); }         \
    else if (tt_ == 30) { asm volatile("s_waitcnt vmcnt(0)" ::: "memory"); }   \
    if (tt_ < 31) __builtin_amdgcn_s_barrier();                                \
    if (tt_ < 31) {                                                            \
      const short* Asn = ring + ((tt_ + 1) & 3) * 16384;                       \
      const short* Bsn = Asn + 8192;                                           \
      _Pragma("unroll")                                                        \
      for (int i_ = 0; i_ < 8; ++i_) AN[i_] = *(const short8*)&Asn[aoff[i_]];  \
      _Pragma("unroll")                                                        \
      for (int j_ = 0; j_ < 4; ++j_) BN2[j_] = *(const short8*)&Bsn[boff[j_]]; \
    }                                                                          \
    if (tt_ <= 28) {                                                           \
      short* dS = ring + ((tt_ + 3) & 3) * 16384;                              \
      const int k0_ = (tt_ + 3) * 32;                                          \
      _Pragma("unroll")                                                        \
      for (int r_ = 0; r_ < 2; ++r_) gll16(Xb + goffA[r_] + k0_, dS + ldsu[r_]); \
      _Pragma("unroll")                                                        \
      for (int r_ = 0; r_ < 2; ++r_) gll16(Wint + goffB[r_] + k0_, dS + 8192 + ldsu[r_]); \
    }                                                                          \
    __builtin_amdgcn_s_setprio(1);                                             \
    _Pragma("unroll")                                                          \
    for (int i_ = 0; i_ < 8; ++i_)                                             \
      _Pragma("unroll")                                                        \
      for (int j_ = 0; j_ < 4; ++j_)                                           \
        acc[i_][j_] = MFMA16(AC[i_], BC[j_], acc[i_][j_]);                     \
    __builtin_amdgcn_s_setprio(0);                                             \
  }

__global__ __launch_bounds__(512, 2) void gemm_x4w(
    const short* __restrict__ Xb, const short* __restrict__ Wint,
    short* __restrict__ qout, short* __restrict__ kT, short* __restrict__ vT,
    float* __restrict__ ssk, float* __restrict__ ssv) {
  __shared__ short ring[4 * 16384];  // 128 KB; epilogue reuses front as 64x264

  const int t = threadIdx.x;
  const int w = t >> 6;
  const int lane = t & 63;
  const int l16 = lane & 15;
  const int quad = lane >> 4;
  const int wm = w >> 2;
  const int wn = w & 3;

  // XCD-aware bijective swizzle (2048 blocks % 8 == 0)
  const int bid = blockIdx.x;
  const int lin = (bid & 7) * 256 + (bid >> 3);
  const int mt = lin >> 4;
  const int nt = lin & 15;
  const int M0 = mt * 256;
  const int N0 = nt * 256;
  const int E0 = nt * 64;

  const float4_t fz = {0.f, 0.f, 0.f, 0.f};
  float4_t acc[8][4];
#pragma unroll
  for (int i = 0; i < 8; ++i)
#pragma unroll
    for (int j2 = 0; j2 < 4; ++j2) acc[i][j2] = fz;

  size_t goffA[2], goffB[2];
  int ldsu[2];
#pragma unroll
  for (int r = 0; r < 2; ++r) {
    const int uu = w * 2 + r;
    const int row = uu * 16 + (lane >> 2);
    const int sp = (lane & 3) ^ ((row >> 1) & 3);
    goffA[r] = (size_t)(M0 + row) * 1024 + sp * 8;
    goffB[r] = (size_t)(N0 + row) * 1024 + sp * 8;
    ldsu[r] = uu * 512;
  }
  int aoff[8], boff[4];
#pragma unroll
  for (int i = 0; i < 8; ++i) {
    const int row = wm * 128 + i * 16 + l16;
    aoff[i] = row * 32 + ((quad ^ ((row >> 1) & 3)) << 3);
  }
#pragma unroll
  for (int j2 = 0; j2 < 4; ++j2) {
    const int row = wn * 64 + j2 * 16 + l16;
    boff[j2] = row * 32 + ((quad ^ ((row >> 1) & 3)) << 3);
  }

  // prologue: stage slots 0,1,2 (12 gll/lane in flight)
#pragma unroll
  for (int s = 0; s < 3; ++s) {
#pragma unroll
    for (int r = 0; r < 2; ++r) gll16(Xb + goffA[r] + s * 32, ring + s * 16384 + ldsu[r]);
#pragma unroll
    for (int r = 0; r < 2; ++r) gll16(Wint + goffB[r] + s * 32, ring + s * 16384 + 8192 + ldsu[r]);
  }
  asm volatile("s_waitcnt vmcnt(4)" ::: "memory");  // slots 0,1 landed; 2 may fly
  __builtin_amdgcn_s_barrier();

  short8 aFA[8], bFA[4], aFB[8], bFB[4];
  // reads(0) into buffer A
#pragma unroll
  for (int i = 0; i < 8; ++i) aFA[i] = *(const short8*)&ring[aoff[i]];
#pragma unroll
  for (int j2 = 0; j2 < 4; ++j2) bFA[j2] = *(const short8*)&ring[8192 + boff[j2]];

#pragma unroll 1
  for (int tt = 0; tt < 32; tt += 2) {
    X4W_STEP(tt, aFA, bFA, aFB, bFB);      // MFMA on A, load B
    X4W_STEP(tt + 1, aFB, bFB, aFA, bFA);  // MFMA on B, load A
  }

  // epilogue 1: query = relu*relu -> bf16 [bn][e]
  const int e = E0 + wn * 16 + l16;
#pragma unroll
  for (int i = 0; i < 8; ++i) {
    const int rowg = M0 + wm * 128 + i * 16 + quad * 4;
#pragma unroll
    for (int rr = 0; rr < 4; ++rr) {
      float v = fmaxf(acc[i][0][rr], 0.f) * fmaxf(acc[i][1][rr], 0.f);
      qout[(size_t)(rowg + rr) * 1024 + e] = f2b(v);
    }
  }

  // epilogue 2: k,v transposed -> [b][e][n] + sumsq
  short* T = ring;
  const int b = M0 >> 12;
  const int n0 = M0 & 4095;
#pragma unroll
  for (int wt = 2; wt < 4; ++wt) {
    short* dst = (wt == 2) ? kT : vT;
    float* ss = (wt == 2) ? ssk : ssv;
    __syncthreads();
#pragma unroll
    for (int i = 0; i < 8; ++i) {
      const int nl = wm * 128 + i * 16 + quad * 4;
      const int el = wn * 16 + l16;
      short4_t pk;
#pragma unroll
      for (int rr = 0; rr < 4; ++rr) pk[rr] = f2b(acc[i][wt][rr]);
      *(short4_t*)&T[el * 264 + nl] = pk;
    }
    __syncthreads();
#pragma unroll
    for (int it = 0; it < 4; ++it) {
      const int ee = it * 16 + (t >> 5);
      const int nch = (t & 31) * 8;
      short8 vv = *(const short8*)&T[ee * 264 + nch];
      *(short8*)&dst[((size_t)b * 1024 + E0 + ee) * 4096 + n0 + nch] = vv;
      float s = 0.f;
#pragma unroll
      for (int x2 = 0; x2 < 8; ++x2) { float f = b2f(vv[x2]); s += f * f; }
      s += __shfl_xor(s, 1, 32);
      s += __shfl_xor(s, 2, 32);
      s += __shfl_xor(s, 4, 32);
      s += __shfl_xor(s, 8, 32);
      s += __shfl_xor(s, 16, 32);
      if ((t & 31) == 0) atomicAdd(&ss[b * 1024 + E0 + ee], s);
    }
  }
}

// ---------------------------------------------------------------------------
// Kernel 2: inv norms
// ---------------------------------------------------------------------------
__global__ void finish_norms(const float* __restrict__ ss, float* __restrict__ inv) {
  const int i = blockIdx.x * 256 + threadIdx.x;
  if (i < 2 * BATCH_ * D_) inv[i] = 1.f / (sqrtf(ss[i]) + 1e-5f);
}

// ---------------------------------------------------------------------------
// Kernel 3: phased batched gemm_bt_p (128m x 256n, BK=32, 4-slot ring 96KB).
// R6: same read-ahead-one-step schedule as gemm_x4w.
// mode 0: out bf16 = relu(C * rs[m] * cs[n]);  mode 1: out fp32 NT.
// ---------------------------------------------------------------------------
#define BTP_STEP(TT, AC, BC, AN, BN2)                                          \
  {                                                                            \
    const int tt_ = (TT);                                                      \
    if (tt_ < NT - 2) { asm volatile("s_waitcnt vmcnt(3)" ::: "memory"); }     \
    else if (tt_ == NT - 2) { asm volatile("s_waitcnt vmcnt(0)" ::: "memory"); } \
    if (tt_ < NT - 1) __builtin_amdgcn_s_barrier();                            \
    if (tt_ < NT - 1) {                                                        \
      const short* Sn = ring + ((tt_ + 1) & 3) * 12288;                        \
      _Pragma("unroll")                                                        \
      for (int i_ = 0; i_ < 4; ++i_) AN[i_] = *(const short8*)&Sn[aoff[i_]];   \
      _Pragma("unroll")                                                        \
      for (int j_ = 0; j_ < 4; ++j_) BN2[j_] = *(const short8*)&Sn[boff[j_]];  \
    }                                                                          \
    if (tt_ <= NT - 4) {                                                       \
      short* dS = ring + ((tt_ + 3) & 3) * 12288;                              \
      const int k0_ = (tt_ + 3) * 32;                                          \
      _Pragma("unroll")                                                        \
      for (int r_ = 0; r_ < 3; ++r_) gll16(gptr[r_] + k0_, dS + ldso[r_]);     \
    }                                                                          \
    __builtin_amdgcn_s_setprio(1);                                             \
    _Pragma("unroll")                                                          \
    for (int i_ = 0; i_ < 4; ++i_)                                             \
      _Pragma("unroll")                                                        \
      for (int j_ = 0; j_ < 4; ++j_)                                           \
        acc[i_][j_] = MFMA16(AC[i_], BC[j_], acc[i_][j_]);                     \
    __builtin_amdgcn_s_setprio(0);                                             \
  }

__global__ __launch_bounds__(512, 2) void gemm_bt_p(
    const short* __restrict__ A, const short* __restrict__ Bm,
    size_t sAb, size_t sBb, int K, int mode,
    const float* __restrict__ rsb, const float* __restrict__ csb,
    void* __restrict__ outp) {
  __shared__ short ring[4 * 12288];  // 96 KB

  const int t = threadIdx.x;
  const int w = t >> 6;
  const int lane = t & 63;
  const int l16 = lane & 15;
  const int quad = lane >> 4;
  const int wm = w >> 2;
  const int wn = w & 3;
  const int M0 = blockIdx.y * 128, N0 = blockIdx.x * 256, b = blockIdx.z;
  const short* Ab = A + (size_t)b * sAb;
  const short* Bb = Bm + (size_t)b * sBb;
  const int NT = K >> 5;

  const float4_t fz = {0.f, 0.f, 0.f, 0.f};
  float4_t acc[4][4];
#pragma unroll
  for (int i = 0; i < 4; ++i)
#pragma unroll
    for (int j = 0; j < 4; ++j) acc[i][j] = fz;

  // staging units: wave w owns u = 3w..3w+2; u<8 A, u>=8 B
  const short* gptr[3];
  int ldso[3];
#pragma unroll
  for (int r = 0; r < 3; ++r) {
    const int u = w * 3 + r;
    const int lrow = (u < 8 ? u * 16 : (u - 8) * 16) + (lane >> 2);
    const int sp = (lane & 3) ^ ((lrow >> 1) & 3);
    gptr[r] = (u < 8 ? Ab + (size_t)(M0 + lrow) * K : Bb + (size_t)(N0 + lrow) * K) + sp * 8;
    ldso[r] = (u < 8 ? u * 512 : 4096 + (u - 8) * 512);
  }
  int aoff[4], boff[4];
#pragma unroll
  for (int i = 0; i < 4; ++i) {
    const int row = wm * 64 + i * 16 + l16;
    aoff[i] = row * 32 + ((quad ^ ((row >> 1) & 3)) << 3);
  }
#pragma unroll
  for (int j = 0; j < 4; ++j) {
    const int row = wn * 64 + j * 16 + l16;
    boff[j] = 4096 + row * 32 + ((quad ^ ((row >> 1) & 3)) << 3);
  }

  // prologue: stage slots 0,1,2 (9 gll/lane in flight)
#pragma unroll
  for (int s = 0; s < 3; ++s)
#pragma unroll
    for (int r = 0; r < 3; ++r) gll16(gptr[r] + s * 32, ring + s * 12288 + ldso[r]);
  asm volatile("s_waitcnt vmcnt(3)" ::: "memory");  // slots 0,1 landed
  __builtin_amdgcn_s_barrier();

  short8 aFA[4], bFA[4], aFB[4], bFB[4];
#pragma unroll
  for (int i = 0; i < 4; ++i) aFA[i] = *(const short8*)&ring[aoff[i]];
#pragma unroll
  for (int j = 0; j < 4; ++j) bFA[j] = *(const short8*)&ring[boff[j]];

#pragma unroll 1
  for (int tt = 0; tt < NT; tt += 2) {
    BTP_STEP(tt, aFA, bFA, aFB, bFB);
    BTP_STEP(tt + 1, aFB, bFB, aFA, bFA);
  }

  if (mode == 0) {
    short* ob = (short*)outp + (size_t)b * D_ * D_;
    const float* rs = rsb + b * D_ + M0;
    const float* cs = csb + b * D_ + N0;
#pragma unroll
    for (int i = 0; i < 4; ++i) {
      const int rl = wm * 64 + i * 16 + quad * 4;
#pragma unroll
      for (int j = 0; j < 4; ++j) {
        const int cl = wn * 64 + j * 16 + l16;
        const float csc = cs[cl];
#pragma unroll
        for (int rr = 0; rr < 4; ++rr) {
          float v = acc[i][j][rr] * rs[rl + rr] * csc;
          v = fmaxf(v, 0.f);
          ob[(size_t)(M0 + rl + rr) * 1024 + (N0 + cl)] = f2b(v);
        }
      }
    }
  } else {
    float* of = (float*)outp + (size_t)b * NSEQ_ * D_;
#pragma unroll
    for (int i = 0; i < 4; ++i) {
      const int rl = wm * 64 + i * 16 + quad * 4;
#pragma unroll
      for (int j = 0; j < 4; ++j) {
        const int cl = wn * 64 + j * 16 + l16;
#pragma unroll
        for (int rr = 0; rr < 4; ++rr)
          __builtin_nontemporal_store(acc[i][j][rr],
                                      &of[(size_t)(M0 + rl + rr) * 1024 + (N0 + cl)]);
      }
    }
  }
}

// ---------------------------------------------------------------------------
extern "C" void kernel_launch(void* const* d_in, const int* in_sizes, int n_in,
                              void* d_out, int out_size, void* d_ws, size_t ws_size,
                              hipStream_t stream) {
  const float* x = (const float*)d_in[0];
  const float* wqr = (const float*)d_in[1];
  const float* wqi = (const float*)d_in[2];
  const float* wk = (const float*)d_in[3];
  const float* wv = (const float*)d_in[4];

  // workspace layout (all bf16 stored as short)
  short* wT = (short*)d_ws;                          // 4 * D*D            (8 MB)
  short* qb = wT + (size_t)4 * D_ * D_;              // BN * D             (64 MB)
  short* kT = qb + (size_t)BN_ * D_;                 // B * D * N          (64 MB)
  short* vT = kT + (size_t)BATCH_ * D_ * NSEQ_;      // B * D * N          (64 MB)
  short* kvT = vT + (size_t)BATCH_ * D_ * NSEQ_;     // B * D * D          (16 MB)
  float* ssk = (float*)(kvT + (size_t)BATCH_ * D_ * D_);  // B*D
  float* ssv = ssk + BATCH_ * D_;                    // B*D
  float* invk = ssv + BATCH_ * D_;                   // B*D
  float* invv = invk + BATCH_ * D_;                  // B*D

  // bf16 x parked in d_out (only overwritten by the final GEMM, which runs
  // strictly after x's last use)
  short* xb = (short*)d_out;

  hipMemsetAsync(ssk, 0, (size_t)2 * BATCH_ * D_ * sizeof(float), stream);

  convert_x<<<dim3(16384), 256, 0, stream>>>(x, xb);

  transpose_convert_w<<<dim3(32, 32, 4), dim3(32, 8), 0, stream>>>(wqr, wqi, wk, wv, wT);

  gemm_x4w<<<dim3(2048), 512, 0, stream>>>(xb, wT, qb, kT, vT, ssk, ssv);

  finish_norms<<<dim3(64), 256, 0, stream>>>(ssk, invk);

  // kv^T[b][e][d] = relu( (sum_n V[n,e]K[n,d]) * invv[e] * invk[d] )
  gemm_bt_p<<<dim3(4, 8, 8), 512, 0, stream>>>(
      vT, kT, (size_t)D_ * NSEQ_, (size_t)D_ * NSEQ_, 4096, 0, invv, invk, (void*)kvT);

  // out[b][n][e] = sum_d query[n,d] * kv^T[e,d]   (fp32)
  gemm_bt_p<<<dim3(4, 32, 8), 512, 0, stream>>>(
      qb, kvT, (size_t)NSEQ_ * D_, (size_t)D_ * D_, 1024, 1, nullptr, nullptr, d_out);
}